// Round 3
// baseline (4198.699 us; speedup 1.0000x reference)
//
#include <hip/hip_runtime.h>
#include <stdint.h>

// ============================================================================
// Reformer/LSH iTransformer forward on MI355X (gfx950). ALL I/O IS FP32.
// GEMMs: bf16 MFMA with BOTH operands split hi/lo bf16 in the LDS stager,
// 3 MFMAs per K-step (AhiBhi+AloBhi+AhiBlo) => ~1e-5-relative activations so
// the LSH bucket argmax matches the np fp32 reference (discrete routing).
// Softmax / LN / bucket / sort math in fp32.
// ============================================================================

constexpr int B_=32, L_=512, E_=512, NMARK_=4, D_=512, DFF_=2048, NLAYERS_=2;
constexpr int NTOK=516, TPAD=520, DH_=64, NB_=130, NHASH_=4;
constexpr int BH_=256, NCH_=520;   // batch*heads, chunks per bh (4 rounds x 130)

typedef __attribute__((ext_vector_type(8))) short v8s;
typedef __attribute__((ext_vector_type(4))) float v4f;

static __device__ __forceinline__ unsigned short f2bf(float f){
  union{float f; unsigned int u;} c; c.f=f;
  unsigned int u=c.u;
  return (unsigned short)((u + 0x7fffu + ((u>>16)&1u))>>16);  // RNE
}
static __device__ __forceinline__ float bf2f(unsigned short h){
  union{unsigned int u; float f;} c; c.u=((unsigned int)h)<<16; return c.f;
}
static __device__ __forceinline__ float blockReduce256(float v, float* red, int tid){
  for(int o=32;o;o>>=1) v += __shfl_down(v,o,64);
  __syncthreads();
  if((tid&63)==0) red[tid>>6]=v;
  __syncthreads();
  return red[0]+red[1]+red[2]+red[3];
}

// ---------------- RevIN stats over L per (b,e) ------------------------------
__global__ __launch_bounds__(256) void k_revin(const float* __restrict__ xe,
    float* __restrict__ means, float* __restrict__ stdev){
  int b=blockIdx.y;
  int e=blockIdx.x*256+threadIdx.x;
  const float* p = xe + (size_t)b*L_*E_ + e;
  float s=0.f,s2=0.f;
  for(int l=0;l<L_;l++){ float v=p[(size_t)l*E_]; s+=v; s2+=v*v; }
  float m=s*(1.f/512.f);
  float var=s2*(1.f/512.f)-m*m;
  var = var>0.f? var:0.f;
  means[b*E_+e]=m;
  stdev[b*E_+e]=sqrtf(var+1e-5f);
}

// ------- transpose x_enc -> tok rows (c<512) with RevIN normalize ----------
__global__ __launch_bounds__(256) void k_pack_tok(const float* __restrict__ xe,
     const float* __restrict__ means, const float* __restrict__ stdev,
     float* __restrict__ tok){
  __shared__ float tile[64][65];
  int b=blockIdx.z;
  int ct=blockIdx.x*64, lt=blockIdx.y*64;
  int tid=threadIdx.x;
  int i=tid>>2, j0=(tid&3)*16;
  {
    const float* src = xe + ((size_t)b*L_ + lt + i)*E_ + ct + j0;
    float tmp[16];
    *(float4*)&tmp[0]  = *(const float4*)(src);
    *(float4*)&tmp[4]  = *(const float4*)(src+4);
    *(float4*)&tmp[8]  = *(const float4*)(src+8);
    *(float4*)&tmp[12] = *(const float4*)(src+12);
    for(int j=0;j<16;j++) tile[i][j0+j]=tmp[j];
  }
  __syncthreads();
  {
    float ms=means[b*E_+ct+i];
    float sd=stdev[b*E_+ct+i];
    float o[16];
    for(int j=0;j<16;j++) o[j]=(tile[j0+j][i]-ms)/sd;
    float* dst = tok + ((size_t)b*NTOK + ct + i)*(size_t)L_ + lt + j0;
    *(float4*)&dst[0]  = *(float4*)&o[0];
    *(float4*)&dst[4]  = *(float4*)&o[4];
    *(float4*)&dst[8]  = *(float4*)&o[8];
    *(float4*)&dst[12] = *(float4*)&o[12];
  }
}

__global__ void k_pack_marks(const float* __restrict__ xm,
    float* __restrict__ tok){
  int idx=blockIdx.x*256+threadIdx.x; // 32*4*512
  int l=idx&511, j=(idx>>9)&3, b=idx>>11;
  tok[((size_t)b*NTOK + E_ + j)*(size_t)L_ + l] = xm[((size_t)b*L_ + l)*NMARK_ + j];
}

// ---------------- 128x128 split-bf16 MFMA GEMM: C = A @ B^T + bias ----------
// A: fp32 [M][K]; B: fp32 [N][K]. Both hi/lo-split in the stager; 3 MFMAs.
// K%32==0, M%128==0. TPADDED: M rows are b*520+t; A read from compact
// [b*516+t], rows t>=516 are zeros. RELU: relu before store.
template<int RELU, bool TPADDED>
__global__ __launch_bounds__(256) void k_gemm(
    const float* __restrict__ Af, const float* __restrict__ Bw,
    const float* __restrict__ bias, float* __restrict__ Cf,
    int M, int N, int K)
{
  constexpr int PADW=40;  // 32 + 8 pad
  __shared__ __align__(16) unsigned short As[128*PADW];
  __shared__ __align__(16) unsigned short Al[128*PADW];
  __shared__ __align__(16) unsigned short Bs[128*PADW];
  __shared__ __align__(16) unsigned short Bl[128*PADW];
  const int m0=blockIdx.y*128, n0=blockIdx.x*128;
  const int tid=threadIdx.x, lane=tid&63, wave=tid>>6;
  const int wm=(wave>>1)*64, wn=(wave&1)*64;
  const int srow=tid>>1, sseg=(tid&1)*16;
  const float* arow;
  bool avalid=true;
  if constexpr (TPADDED){
    int g=m0+srow; int b=g/TPAD; int t=g-b*TPAD;
    avalid=(t<NTOK);
    arow=Af + ((size_t)b*NTOK + (avalid?t:0))*(size_t)K;
  } else {
    arow=Af + (size_t)(m0+srow)*(size_t)K;
  }
  const float* brow = Bw + (size_t)(n0+srow)*(size_t)K;
  v4f acc[4][4];
  for(int i=0;i<4;i++)for(int j=0;j<4;j++) acc[i][j]=(v4f){0.f,0.f,0.f,0.f};
  const int am = wm + (lane&15);
  const int bn = wn + (lane&15);
  const int kk = (lane>>4)*8;
  for(int k0=0;k0<K;k0+=32){
    __syncthreads();
    {
      float av[16];
      if(avalid){
        const float4* g4=(const float4*)(arow + k0 + sseg);
        *(float4*)&av[0]=g4[0]; *(float4*)&av[4]=g4[1];
        *(float4*)&av[8]=g4[2]; *(float4*)&av[12]=g4[3];
      } else {
        for(int j=0;j<16;j++) av[j]=0.f;
      }
      unsigned short hs[16], ls[16];
      for(int j=0;j<16;j++){
        unsigned short hh=f2bf(av[j]);
        hs[j]=hh; ls[j]=f2bf(av[j]-bf2f(hh));
      }
      *(uint4*)&As[srow*PADW+sseg]   = *(uint4*)&hs[0];
      *(uint4*)&As[srow*PADW+sseg+8] = *(uint4*)&hs[8];
      *(uint4*)&Al[srow*PADW+sseg]   = *(uint4*)&ls[0];
      *(uint4*)&Al[srow*PADW+sseg+8] = *(uint4*)&ls[8];
      float bv16[16];
      {
        const float4* g4=(const float4*)(brow + k0 + sseg);
        *(float4*)&bv16[0]=g4[0]; *(float4*)&bv16[4]=g4[1];
        *(float4*)&bv16[8]=g4[2]; *(float4*)&bv16[12]=g4[3];
      }
      for(int j=0;j<16;j++){
        unsigned short hh=f2bf(bv16[j]);
        hs[j]=hh; ls[j]=f2bf(bv16[j]-bf2f(hh));
      }
      *(uint4*)&Bs[srow*PADW+sseg]   = *(uint4*)&hs[0];
      *(uint4*)&Bs[srow*PADW+sseg+8] = *(uint4*)&hs[8];
      *(uint4*)&Bl[srow*PADW+sseg]   = *(uint4*)&ls[0];
      *(uint4*)&Bl[srow*PADW+sseg+8] = *(uint4*)&ls[8];
    }
    __syncthreads();
    v8s a[4], al[4], b[4], bl[4];
    for(int t=0;t<4;t++){
      a[t] =*(const v8s*)&As[(am+t*16)*PADW+kk];
      al[t]=*(const v8s*)&Al[(am+t*16)*PADW+kk];
      b[t] =*(const v8s*)&Bs[(bn+t*16)*PADW+kk];
      bl[t]=*(const v8s*)&Bl[(bn+t*16)*PADW+kk];
    }
    for(int mt=0;mt<4;mt++)for(int nt=0;nt<4;nt++){
      acc[mt][nt]=__builtin_amdgcn_mfma_f32_16x16x32_bf16(al[mt],b[nt], acc[mt][nt],0,0,0);
      acc[mt][nt]=__builtin_amdgcn_mfma_f32_16x16x32_bf16(a[mt], bl[nt],acc[mt][nt],0,0,0);
      acc[mt][nt]=__builtin_amdgcn_mfma_f32_16x16x32_bf16(a[mt], b[nt], acc[mt][nt],0,0,0);
    }
  }
  // C/D mapping: col=lane&15, row=(lane>>4)*4+r (m89-verified)
  for(int mt=0;mt<4;mt++)for(int nt=0;nt<4;nt++){
    int col = n0 + wn + nt*16 + (lane&15);
    int rb  = m0 + wm + mt*16 + (lane>>4)*4;
    float bv = bias ? bias[col] : 0.f;
    for(int r=0;r<4;r++){
      float v = acc[mt][nt][r] + bv;
      if constexpr (RELU) v = v>0.f ? v : 0.f;
      Cf[(size_t)(rb+r)*N + col] = v;
    }
  }
}

// ---------------- LSH buckets: argmax over [rot,-rot] (130), fp32 -----------
// Block: one (bh, t-slice, hash-pair). LDS holds 2 hashes of rot in fp32.
__global__ __launch_bounds__(256) void k_buckets(const float* __restrict__ qk,
    const float* __restrict__ rot, unsigned char* __restrict__ buckets){
  __shared__ float rl[64*130];     // [f][hh*65+i] for this hash pair
  __shared__ float qrow[64];
  __shared__ float pv[4][2];
  __shared__ int   pi[4][2];
  int bh=blockIdx.x, slice=blockIdx.y, hg=blockIdx.z;
  int b=bh>>3, hd=bh&7;
  int tid=threadIdx.x, wave=tid>>6, lane=tid&63;
  for(int j=tid;j<64*130;j+=256){
    int f=j/130, rem=j-f*130;
    rl[j]=rot[f*260 + hg*130 + rem];
  }
  int hh=tid&1, ii=tid>>1;
  bool act=(ii<=64);
  const float* qbase = qk + (size_t)b*TPAD*D_ + (size_t)hd*64;
  for(int t=slice*130; t<slice*130+130; t++){
    __syncthreads();
    if(tid<64) qrow[tid]=qbase[(size_t)t*D_+tid];
    __syncthreads();
    float bv=-3.4e38f; int bi=0x7fffffff;
    if(act){
      float r=0.f;
      for(int f=0;f<64;f++) r += qrow[f]*rl[f*130 + hh*65 + ii];
      if(r >= -r){ bv=r; bi=ii; } else { bv=-r; bi=ii+65; }
    }
    for(int m=2;m<64;m<<=1){  // parity-preserving: reduces over ii within wave
      float ov=__shfl_xor(bv,m,64); int oi=__shfl_xor(bi,m,64);
      if(ov>bv || (ov==bv && oi<bi)){ bv=ov; bi=oi; }
    }
    if(lane<2){ pv[wave][lane]=bv; pi[wave][lane]=bi; }
    __syncthreads();
    if(tid<2){
      float BV=pv[0][tid]; int BI=pi[0][tid];
      for(int w2=1;w2<4;w2++){
        float ov=pv[w2][tid]; int oi=pi[w2][tid];
        if(ov>BV || (ov==BV && oi<BI)){ BV=ov; BI=oi; }
      }
      buckets[((size_t)bh*4 + hg*2+tid)*TPAD + t] = (unsigned char)BI;
    }
  }
}

// ---------------- stable counting sort == jnp.argsort(bucket*t+pos) ---------
__global__ __launch_bounds__(64) void k_sort(const unsigned char* __restrict__ buckets,
    unsigned short* __restrict__ sticker, unsigned short* __restrict__ undo){
  __shared__ int cnt[520];
  __shared__ int offs[520];
  int bh=blockIdx.x, tid=threadIdx.x;
  const unsigned char* bb = buckets + (size_t)bh*4*TPAD;
  for(int i=tid;i<520;i+=64) cnt[i]=0;
  __syncthreads();
  for(int i=tid;i<2080;i+=64){
    int h=i/TPAD;
    atomicAdd(&cnt[(int)bb[i]+h*NB_],1);
  }
  __syncthreads();
  if(tid==0){ int s=0; for(int k2=0;k2<520;k2++){ offs[k2]=s; s+=cnt[k2]; } }
  __syncthreads();
  if(tid<4){  // per-hash bins disjoint -> 4 independent stable scatters
    int h=tid;
    unsigned short* stk = sticker + (size_t)bh*2080;
    unsigned short* ud  = undo    + (size_t)bh*2080;
    for(int p=0;p<TPAD;p++){
      int key = (int)bb[h*TPAD+p] + h*NB_;
      int j = offs[key]++;
      stk[j] = (unsigned short)(h*TPAD+p);
      ud[h*TPAD+p] = (unsigned short)j;
    }
  }
}

// ---------------- attention pass 1: per-chunk LSE (sorted space) ------------
__global__ __launch_bounds__(256) void k_attn1(const float* __restrict__ qk,
    const unsigned short* __restrict__ sticker, float* __restrict__ lse){
  __shared__ float rows[8][8][65];
  __shared__ int   sts[8][8];
  __shared__ float n2s[8][8];
  int tid=threadIdx.x, grp=tid>>5, lane=tid&31;
  int gid=blockIdx.x*8+grp;
  int bh=gid/NCH_, c=gid-bh*NCH_;
  int b=bh>>3, hd=bh&7;
  const unsigned short* stk = sticker + (size_t)bh*2080;
  if(lane<8){
    int r=lane;
    int cprev=(c+NCH_-1)%NCH_;
    int j=(r<4)? c*4+r : cprev*4+(r-4);
    sts[grp][r]=(int)stk[j]%TPAD;
  }
  __syncthreads();
  for(int idx=lane; idx<512; idx+=32){
    int r=idx>>6, f=idx&63;
    rows[grp][r][f]=qk[((size_t)b*TPAD+sts[grp][r])*(size_t)D_+hd*64+f];
  }
  __syncthreads();
  {
    int r=lane>>2, part=lane&3;
    float s=0.f;
    for(int f=part*16; f<part*16+16; f++){ float v=rows[grp][r][f]; s+=v*v; }
    s+=__shfl_xor(s,1,64); s+=__shfl_xor(s,2,64);
    if(part==0) n2s[grp][r]=s;
  }
  __syncthreads();
  int qi=lane>>3, kj=lane&7;
  float dt=0.f;
  for(int f=0;f<64;f++) dt += rows[grp][qi][f]*rows[grp][kj][f];
  float kn=n2s[grp][kj]; kn = kn>1e-24f? kn:1e-24f;
  dt = dt/sqrtf(kn)*0.125f;
  if(sts[grp][qi]==sts[grp][kj]) dt=-5e4f;
  float mx=dt;
  for(int o=1;o<8;o<<=1){ float om=__shfl_xor(mx,o,64); mx=om>mx?om:mx; }
  float sm=expf(dt-mx);
  for(int o=1;o<8;o<<=1) sm+=__shfl_xor(sm,o,64);
  if(kj==0) lse[(size_t)bh*2080 + c*4 + qi] = mx + logf(sm);
}

// ---------------- attention pass 2: per-(slot,key) probs with round weight --
__global__ __launch_bounds__(256) void k_probs(const float* __restrict__ qk,
    const unsigned short* __restrict__ sticker, const unsigned short* __restrict__ undo,
    const float* __restrict__ lse, float* __restrict__ PR){
  __shared__ float rows[8][8][65];
  __shared__ int   sts[8][8];
  __shared__ float n2s[8][8];
  __shared__ float wq[8][4];
  int tid=threadIdx.x, grp=tid>>5, lane=tid&31;
  int gid=blockIdx.x*8+grp;
  int bh=gid/NCH_, c=gid-bh*NCH_;
  int b=bh>>3, hd=bh&7;
  const unsigned short* stk = sticker + (size_t)bh*2080;
  if(lane<8){
    int r=lane;
    int cprev=(c+NCH_-1)%NCH_;
    int j=(r<4)? c*4+r : cprev*4+(r-4);
    sts[grp][r]=(int)stk[j]%TPAD;
  }
  __syncthreads();
  for(int idx=lane; idx<512; idx+=32){
    int r=idx>>6, f=idx&63;
    rows[grp][r][f]=qk[((size_t)b*TPAD+sts[grp][r])*(size_t)D_+hd*64+f];
  }
  __syncthreads();
  {
    int r=lane>>2, part=lane&3;
    float s=0.f;
    for(int f=part*16; f<part*16+16; f++){ float v=rows[grp][r][f]; s+=v*v; }
    s+=__shfl_xor(s,1,64); s+=__shfl_xor(s,2,64);
    if(part==0) n2s[grp][r]=s;
  }
  __syncthreads();
  int qi=lane>>3, kj=lane&7;
  float dt=0.f;
  for(int f=0;f<64;f++) dt += rows[grp][qi][f]*rows[grp][kj][f];
  float kn=n2s[grp][kj]; kn = kn>1e-24f? kn:1e-24f;
  dt = dt/sqrtf(kn)*0.125f;
  if(sts[grp][qi]==sts[grp][kj]) dt=-5e4f;
  float L = lse[(size_t)bh*2080 + c*4 + qi];
  if(kj==0){
    int p = sts[grp][qi];
    const unsigned short* ud = undo + (size_t)bh*2080;
    const float* ls = lse + (size_t)bh*2080;
    float l0=ls[ud[p]],        l1=ls[ud[TPAD+p]];
    float l2=ls[ud[2*TPAD+p]], l3=ls[ud[3*TPAD+p]];
    float mx2=fmaxf(fmaxf(l0,l1),fmaxf(l2,l3));
    float s=expf(l0-mx2)+expf(l1-mx2)+expf(l2-mx2)+expf(l3-mx2);
    wq[grp][qi]=expf(L-mx2)/s;
  }
  __syncthreads();
  PR[((size_t)bh*2080 + c*4 + qi)*8 + kj] = expf(dt-L)*wq[grp][qi];
}

// ---------------- attention gather: out[b,t,:] = sum_h sum_kj P * v ---------
__global__ __launch_bounds__(256) void k_gather(const float* __restrict__ v,
    const unsigned short* __restrict__ sticker, const unsigned short* __restrict__ undo,
    const float* __restrict__ PR, float* __restrict__ attnOut){
  __shared__ int   ridx[8][32];
  __shared__ float pval[8][32];
  int b=blockIdx.x, t=blockIdx.y;       // (32, 516)
  int tid=threadIdx.x, hd=tid>>5, l=tid&31;
  int bh=b*8+hd;
  const unsigned short* stk = sticker + (size_t)bh*2080;
  const unsigned short* ud  = undo    + (size_t)bh*2080;
  {
    int h=l>>3, kj=l&7;
    int j = (int)ud[h*TPAD+t];
    int c = j>>2;
    int slot = (kj<4)? (c*4+kj) : (((c+NCH_-1)%NCH_)*4 + (kj-4));
    ridx[hd][l] = (int)stk[slot]%TPAD;
    pval[hd][l] = PR[((size_t)bh*2080 + j)*8 + kj];
  }
  __syncthreads();
  int f0=l*2;
  float a0=0.f, a1=0.f;
  const float* vb = v + (size_t)b*TPAD*D_ + hd*64 + f0;
  for(int i=0;i<32;i++){
    const float* vr = vb + (size_t)ridx[hd][i]*D_;
    float p=pval[hd][i];
    a0 += p*vr[0];
    a1 += p*vr[1];
  }
  float* ob = attnOut + ((size_t)b*NTOK + t)*(size_t)D_ + hd*64 + f0;
  ob[0]=a0; ob[1]=a1;
}

// ---------------- x = LN(x + delta) * g + b ---------------------------------
__global__ __launch_bounds__(256) void k_addln(float* __restrict__ x,
    const float* __restrict__ delta, const float* __restrict__ g,
    const float* __restrict__ bb){
  __shared__ float red[4];
  int row=blockIdx.x, tid=threadIdx.x;
  size_t base=(size_t)row*D_;
  float v0=x[base+tid]+delta[base+tid];
  float v1=x[base+tid+256]+delta[base+tid+256];
  float m=blockReduce256(v0+v1,red,tid)*(1.f/512.f);
  float d0=v0-m, d1=v1-m;
  float var=blockReduce256(d0*d0+d1*d1,red,tid)*(1.f/512.f);
  float inv=1.f/sqrtf(var+1e-5f);
  x[base+tid]    =d0*inv*g[tid]    +bb[tid];
  x[base+tid+256]=d1*inv*g[tid+256]+bb[tid+256];
}

// ---------------- final LN on last token + projection -----------------------
__global__ __launch_bounds__(256) void k_dec(const float* __restrict__ x,
    const float* __restrict__ gF, const float* __restrict__ bF,
    const float* __restrict__ Wp, const float* __restrict__ bp,
    float* __restrict__ dec){
  __shared__ float red[4];
  int b=blockIdx.x, tid=threadIdx.x;
  const float* row = x + ((size_t)b*NTOK + (NTOK-1))*(size_t)D_;
  float v0=row[tid], v1=row[tid+256];
  float m=blockReduce256(v0+v1,red,tid)*(1.f/512.f);
  float d0=v0-m, d1=v1-m;
  float var=blockReduce256(d0*d0+d1*d1,red,tid)*(1.f/512.f);
  float inv=1.f/sqrtf(var+1e-5f);
  float y0=d0*inv*gF[tid]    +bF[tid];
  float y1=d1*inv*gF[tid+256]+bF[tid+256];
  float dd=blockReduce256(y0*Wp[tid]+y1*Wp[tid+256],red,tid);
  if(tid==0) dec[b]=dd+bp[0];
}

// ---------------- out[i,j,e] = dec[j]*stdev[i,e] + means[i,e] (fp32) --------
__global__ void k_out(const float* __restrict__ dec, const float* __restrict__ means,
    const float* __restrict__ stdev, float* __restrict__ out){
  int idx=blockIdx.x*256+threadIdx.x; // 32*32*512
  int e=idx&511, j=(idx>>9)&31, i=idx>>14;
  out[idx]=dec[j]*stdev[i*E_+e]+means[i*E_+e];
}

// ============================================================================
extern "C" void kernel_launch(void* const* d_in, const int* in_sizes, int n_in,
                              void* d_out, int out_size, void* d_ws, size_t ws_size,
                              hipStream_t stream){
  (void)in_sizes; (void)n_in; (void)out_size; (void)ws_size;
  const float* xe   = (const float*)d_in[0];
  const float* xm   = (const float*)d_in[1];
  const float* Wemb = (const float*)d_in[2];
  const float* bemb = (const float*)d_in[3];
  const float* Wqk  = (const float*)d_in[4];
  const float* Wv   = (const float*)d_in[5];
  const float* Wo   = (const float*)d_in[6];
  const float* boP  = (const float*)d_in[7];
  const float* Wc1  = (const float*)d_in[8];
  const float* bc1  = (const float*)d_in[9];
  const float* Wc2  = (const float*)d_in[10];
  const float* bc2  = (const float*)d_in[11];
  const float* g1   = (const float*)d_in[12];
  const float* b1   = (const float*)d_in[13];
  const float* g2   = (const float*)d_in[14];
  const float* b2   = (const float*)d_in[15];
  const float* gF   = (const float*)d_in[16];
  const float* bF   = (const float*)d_in[17];
  const float* Wp   = (const float*)d_in[18];
  const float* bp   = (const float*)d_in[19];
  const float* rot  = (const float*)d_in[20];
  float* out = (float*)d_out;

  // ---- workspace carve (~124 MB total) ----
  char* w=(char*)d_ws;
  auto carve=[&](size_t n)->char*{ char* p=w; w += (n+255)&~(size_t)255; return p; };
  float* means=(float*)carve(65536);
  float* stdev=(float*)carve(65536);
  float* dec  =(float*)carve(256);
  float* x    =(float*)carve((size_t)B_*NTOK*D_*4);   // 33.8 MB residual fp32
  float* BIG  =(float*)carve((size_t)B_*TPAD*D_*4);   // 34.1 MB: qk/v
  float* SLOT =(float*)carve((size_t)B_*TPAD*D_*4);   // 34.1 MB: tok/attnOut/ffn-hidden
  float* PR   =(float*)carve((size_t)BH_*2080*8*4);   // 17.0 MB probs
  unsigned char*  bkt=(unsigned char*) carve((size_t)BH_*4*TPAD);   // 0.53 MB
  unsigned short* stk=(unsigned short*)carve((size_t)BH_*2080*2);   // 1.06 MB
  unsigned short* ud =(unsigned short*)carve((size_t)BH_*2080*2);   // 1.06 MB
  float* lseB =(float*)carve((size_t)BH_*2080*4);                   // 2.13 MB

  float* tok = SLOT;   // fp32 normalized tokens during embedding only

  // ---- embedding: RevIN applied in the transpose-pack (as reference) ----
  k_revin<<<dim3(2,B_),256,0,stream>>>(xe,means,stdev);
  k_pack_tok<<<dim3(8,8,B_),256,0,stream>>>(xe,means,stdev,tok);
  k_pack_marks<<<(B_*NMARK_*L_)/256,256,0,stream>>>(xm,tok);
  k_gemm<0,false><<<dim3(4,129),256,0,stream>>>(tok,Wemb,bemb,x,16512,512,512);

  // FFN row chunking: 129 row-blocks split as 22+22+22+21+21+21
  const int chunkBlocks[6]={22,22,22,21,21,21};

  for(int l=0;l<NLAYERS_;l++){
    const float* Wqk_l=Wqk+(size_t)l*D_*D_;
    const float* Wv_l =Wv +(size_t)l*D_*D_;
    const float* Wo_l =Wo +(size_t)l*D_*D_;
    const float* bo_l =boP+(size_t)l*D_;
    const float* Wc1_l=Wc1+(size_t)l*DFF_*D_;
    const float* bc1_l=bc1+(size_t)l*DFF_;
    const float* Wc2_l=Wc2+(size_t)l*D_*DFF_;
    const float* bc2_l=bc2+(size_t)l*D_;
    const float* g1_l=g1+(size_t)l*D_;
    const float* b1_l=b1+(size_t)l*D_;
    const float* g2_l=g2+(size_t)l*D_;
    const float* b2_l=b2+(size_t)l*D_;
    const float* rot_l=rot+(size_t)l*DH_*NHASH_*(NB_/2);

    // qk projection (padded rows = 0 via stager predication)
    k_gemm<0,true><<<dim3(4,130),256,0,stream>>>(x,Wqk_l,nullptr,BIG,16640,512,512);
    // LSH routing + exact stable sort
    k_buckets<<<dim3(BH_,4,2),256,0,stream>>>(BIG,rot_l,bkt);
    k_sort<<<BH_,64,0,stream>>>(bkt,stk,ud);
    // LSE then probs (qk consumed after this)
    k_attn1<<<16640,256,0,stream>>>(BIG,stk,lseB);
    k_probs<<<16640,256,0,stream>>>(BIG,stk,ud,lseB,PR);
    // v projection overwrites qk slot; gather writes compact attnOut
    k_gemm<0,true><<<dim3(4,130),256,0,stream>>>(x,Wv_l,nullptr,BIG,16640,512,512);
    k_gather<<<dim3(B_,NTOK),256,0,stream>>>(BIG,stk,ud,PR,SLOT);
    // output projection + residual LN
    k_gemm<0,false><<<dim3(4,129),256,0,stream>>>(SLOT,Wo_l,bo_l,BIG,16512,512,512);
    k_addln<<<16512,256,0,stream>>>(x,BIG,g1_l,b1_l);
    // FFN, row-chunked so fp32 hidden fits SLOT (max 2816x2048x4 = 23.1 MB)
    int rs=0;
    for(int ch=0; ch<6; ch++){
      int nb=chunkBlocks[ch];
      int rows=nb*128;
      k_gemm<1,false><<<dim3(16,nb),256,0,stream>>>(x+(size_t)rs*D_,Wc1_l,bc1_l,SLOT,rows,2048,512);
      k_gemm<0,false><<<dim3(4,nb),256,0,stream>>>(SLOT,Wc2_l,bc2_l,BIG+(size_t)rs*D_,rows,512,2048);
      rs+=rows;
    }
    k_addln<<<16512,256,0,stream>>>(x,BIG,g2_l,b2_l);
  }

  k_dec<<<B_,256,0,stream>>>(x,gF,bF,Wp,bp,dec);
  k_out<<<2048,256,0,stream>>>(dec,means,stdev,out);
}

// Round 5
// 3100.221 us; speedup vs baseline: 1.3543x; 1.3543x over previous
//
#include <hip/hip_runtime.h>
#include <stdint.h>

// ============================================================================
// Reformer/LSH iTransformer forward on MI355X (gfx950). ALL I/O FP32.
// R5 = R4 with the weight-split OOB fixed (Wc1/Wc2 are 2,097,152 elements
// TOTAL; per-layer stride 1,048,576). GEMMs: bf16 MFMA on pre-split hi/lo
// operands, 3 MFMAs/K-step, bit-identical math to the R3 passing run.
// ============================================================================

constexpr int B_=32, L_=512, E_=512, NMARK_=4, D_=512, DFF_=2048, NLAYERS_=2;
constexpr int NTOK=516, TPAD=520, DH_=64, NB_=130, NHASH_=4;
constexpr int BH_=256, NCH_=520;

typedef __attribute__((ext_vector_type(8))) short v8s;
typedef __attribute__((ext_vector_type(4))) float v4f;

static __device__ __forceinline__ unsigned short f2bf(float f){
  union{float f; unsigned int u;} c; c.f=f;
  unsigned int u=c.u;
  return (unsigned short)((u + 0x7fffu + ((u>>16)&1u))>>16);  // RNE
}
static __device__ __forceinline__ float bf2f(unsigned short h){
  union{unsigned int u; float f;} c; c.u=((unsigned int)h)<<16; return c.f;
}
static __device__ __forceinline__ float blockReduce256(float v, float* red, int tid){
  for(int o=32;o;o>>=1) v += __shfl_down(v,o,64);
  __syncthreads();
  if((tid&63)==0) red[tid>>6]=v;
  __syncthreads();
  return red[0]+red[1]+red[2]+red[3];
}

// ---------------- generic fp32 -> (hi,lo) bf16 split ------------------------
__global__ void k_split(const float* __restrict__ src, unsigned short* __restrict__ hi,
    unsigned short* __restrict__ lo, int n){
  int idx=blockIdx.x*256+threadIdx.x;
  if(idx>=n) return;
  float v=src[idx];
  unsigned short h=f2bf(v);
  hi[idx]=h; lo[idx]=f2bf(v-bf2f(h));
}

// ---------------- RevIN stats over L per (b,e) ------------------------------
__global__ __launch_bounds__(256) void k_revin(const float* __restrict__ xe,
    float* __restrict__ means, float* __restrict__ stdev){
  int b=blockIdx.y;
  int e=blockIdx.x*256+threadIdx.x;
  const float* p = xe + (size_t)b*L_*E_ + e;
  float s=0.f,s2=0.f;
  for(int l=0;l<L_;l++){ float v=p[(size_t)l*E_]; s+=v; s2+=v*v; }
  float m=s*(1.f/512.f);
  float var=s2*(1.f/512.f)-m*m;
  var = var>0.f? var:0.f;
  means[b*E_+e]=m;
  stdev[b*E_+e]=sqrtf(var+1e-5f);
}

// ------- transpose x_enc -> token rows with RevIN, split-write hi/lo --------
__global__ __launch_bounds__(256) void k_pack_tok(const float* __restrict__ xe,
     const float* __restrict__ means, const float* __restrict__ stdev,
     unsigned short* __restrict__ hi, unsigned short* __restrict__ lo){
  __shared__ float tile[64][65];
  int b=blockIdx.z;
  int ct=blockIdx.x*64, lt=blockIdx.y*64;
  int tid=threadIdx.x;
  int i=tid>>2, j0=(tid&3)*16;
  {
    const float* src = xe + ((size_t)b*L_ + lt + i)*E_ + ct + j0;
    float tmp[16];
    *(float4*)&tmp[0]  = *(const float4*)(src);
    *(float4*)&tmp[4]  = *(const float4*)(src+4);
    *(float4*)&tmp[8]  = *(const float4*)(src+8);
    *(float4*)&tmp[12] = *(const float4*)(src+12);
    for(int j=0;j<16;j++) tile[i][j0+j]=tmp[j];
  }
  __syncthreads();
  {
    float ms=means[b*E_+ct+i];
    float sd=stdev[b*E_+ct+i];
    unsigned short hs[16], ls[16];
    for(int j=0;j<16;j++){
      float v=(tile[j0+j][i]-ms)/sd;
      unsigned short hh=f2bf(v);
      hs[j]=hh; ls[j]=f2bf(v-bf2f(hh));
    }
    size_t off = ((size_t)b*NTOK + ct + i)*(size_t)L_ + lt + j0;
    *(uint4*)&hi[off]   = *(uint4*)&hs[0];
    *(uint4*)&hi[off+8] = *(uint4*)&hs[8];
    *(uint4*)&lo[off]   = *(uint4*)&ls[0];
    *(uint4*)&lo[off+8] = *(uint4*)&ls[8];
  }
}

__global__ void k_pack_marks(const float* __restrict__ xm,
    unsigned short* __restrict__ hi, unsigned short* __restrict__ lo){
  int idx=blockIdx.x*256+threadIdx.x; // 32*4*512
  int l=idx&511, j=(idx>>9)&3, b=idx>>11;
  float v = xm[((size_t)b*L_ + l)*NMARK_ + j];
  unsigned short hh=f2bf(v);
  size_t off=((size_t)b*NTOK + E_ + j)*(size_t)L_ + l;
  hi[off]=hh; lo[off]=f2bf(v-bf2f(hh));
}

// ---------------- 128x128 bf16 MFMA GEMM on pre-split operands --------------
// C = (Ahi+Alo)@(Bhi+Blo)^T + bias, 3 MFMAs (AloBhi + AhiBlo + AhiBhi).
// OUTMODE 0: fp32 C. OUTMODE 1: relu then split-write hi/lo bf16.
// TPADDED: M rows indexed b*520+t, A read from compact [b*516+t], t>=516 zero.
template<int OUTMODE, bool TPADDED>
__global__ __launch_bounds__(256) void k_gemm(
    const unsigned short* __restrict__ Ahi, const unsigned short* __restrict__ Alo,
    const unsigned short* __restrict__ Bhi, const unsigned short* __restrict__ Blo,
    const float* __restrict__ bias, float* __restrict__ Cf,
    unsigned short* __restrict__ Chi, unsigned short* __restrict__ Clo,
    int M, int N, int K)
{
  constexpr int PADW=40;  // 32 + 8 pad
  __shared__ __align__(16) unsigned short As[128*PADW];
  __shared__ __align__(16) unsigned short Al[128*PADW];
  __shared__ __align__(16) unsigned short Bs[128*PADW];
  __shared__ __align__(16) unsigned short Bl[128*PADW];
  const int m0=blockIdx.y*128, n0=blockIdx.x*128;
  const int tid=threadIdx.x, lane=tid&63, wave=tid>>6;
  const int wm=(wave>>1)*64, wn=(wave&1)*64;
  const int srow=tid>>1, sseg=(tid&1)*16;
  size_t aoff; bool avalid=true;
  if constexpr (TPADDED){
    int g=m0+srow; int b=g/TPAD; int t=g-b*TPAD;
    avalid=(t<NTOK);
    aoff=((size_t)b*NTOK + (avalid?t:0))*(size_t)K;
  } else {
    aoff=(size_t)(m0+srow)*(size_t)K;
  }
  const size_t boff=(size_t)(n0+srow)*(size_t)K;
  v4f acc[4][4];
  for(int i=0;i<4;i++)for(int j=0;j<4;j++) acc[i][j]=(v4f){0.f,0.f,0.f,0.f};
  const int am = wm + (lane&15);
  const int bn = wn + (lane&15);
  const int kk = (lane>>4)*8;
  for(int k0=0;k0<K;k0+=32){
    __syncthreads();
    {
      if(avalid){
        const uint4* ga=(const uint4*)(Ahi+aoff+k0+sseg);
        *(uint4*)&As[srow*PADW+sseg]   = ga[0];
        *(uint4*)&As[srow*PADW+sseg+8] = ga[1];
        const uint4* gl=(const uint4*)(Alo+aoff+k0+sseg);
        *(uint4*)&Al[srow*PADW+sseg]   = gl[0];
        *(uint4*)&Al[srow*PADW+sseg+8] = gl[1];
      } else {
        uint4 z={0,0,0,0};
        *(uint4*)&As[srow*PADW+sseg]=z; *(uint4*)&As[srow*PADW+sseg+8]=z;
        *(uint4*)&Al[srow*PADW+sseg]=z; *(uint4*)&Al[srow*PADW+sseg+8]=z;
      }
      const uint4* gb=(const uint4*)(Bhi+boff+k0+sseg);
      *(uint4*)&Bs[srow*PADW+sseg]   = gb[0];
      *(uint4*)&Bs[srow*PADW+sseg+8] = gb[1];
      const uint4* gbl=(const uint4*)(Blo+boff+k0+sseg);
      *(uint4*)&Bl[srow*PADW+sseg]   = gbl[0];
      *(uint4*)&Bl[srow*PADW+sseg+8] = gbl[1];
    }
    __syncthreads();
    v8s a[4], al[4], b[4], bl[4];
    for(int t=0;t<4;t++){
      a[t] =*(const v8s*)&As[(am+t*16)*PADW+kk];
      al[t]=*(const v8s*)&Al[(am+t*16)*PADW+kk];
      b[t] =*(const v8s*)&Bs[(bn+t*16)*PADW+kk];
      bl[t]=*(const v8s*)&Bl[(bn+t*16)*PADW+kk];
    }
    for(int mt=0;mt<4;mt++)for(int nt=0;nt<4;nt++){
      acc[mt][nt]=__builtin_amdgcn_mfma_f32_16x16x32_bf16(al[mt],b[nt], acc[mt][nt],0,0,0);
      acc[mt][nt]=__builtin_amdgcn_mfma_f32_16x16x32_bf16(a[mt], bl[nt],acc[mt][nt],0,0,0);
      acc[mt][nt]=__builtin_amdgcn_mfma_f32_16x16x32_bf16(a[mt], b[nt], acc[mt][nt],0,0,0);
    }
  }
  // C/D mapping: col=lane&15, row=(lane>>4)*4+r
  for(int mt=0;mt<4;mt++)for(int nt=0;nt<4;nt++){
    int col = n0 + wn + nt*16 + (lane&15);
    int rb  = m0 + wm + mt*16 + (lane>>4)*4;
    float bv = bias ? bias[col] : 0.f;
    for(int r=0;r<4;r++){
      float v = acc[mt][nt][r] + bv;
      size_t off=(size_t)(rb+r)*N + col;
      if constexpr (OUTMODE==0){
        Cf[off]=v;
      } else {
        v = v>0.f ? v : 0.f;
        unsigned short hh=f2bf(v);
        Chi[off]=hh; Clo[off]=f2bf(v-bf2f(hh));
      }
    }
  }
}

// ---------------- LSH buckets: tiled fp32 GEMM + argmax ---------------------
// grid (bh, hash, 9 t-chunks of 64); block 128. Identical fma chain to R3.
__global__ __launch_bounds__(128) void k_buckets(const float* __restrict__ qk,
    const float* __restrict__ rot, unsigned char* __restrict__ buckets){
  __shared__ float qkT[64*68];   // [f][t], pad 68
  __shared__ float rl[64*72];    // [f][i], i<65 real, rest 0
  __shared__ float pv[64*9];
  __shared__ int   pi[64*9];
  int bh=blockIdx.x, h=blockIdx.y, tc=blockIdx.z;
  int b=bh>>3, hd=bh&7;
  int t0=tc*64;
  int tid=threadIdx.x;
  for(int j=tid;j<64*72;j+=128){
    int f=j/72, i=j-72*f;
    rl[j]=(i<65)? rot[f*260 + h*65 + i] : 0.f;
  }
  for(int j=tid;j<4096;j+=128){
    int t=j>>6, f=j&63;
    int tg=t0+t;
    qkT[f*68+t] = (tg<TPAD)? qk[((size_t)b*TPAD+tg)*(size_t)D_ + hd*64 + f] : 0.f;
  }
  __syncthreads();
  for(int task=tid; task<144; task+=128){
    int tg=task&15, cg=task>>4;      // 4 t-rows, 8 cols
    float acc[4][8];
    for(int i=0;i<4;i++)for(int j=0;j<8;j++) acc[i][j]=0.f;
    for(int f=0;f<64;f++){
      float4 a = *(float4*)&qkT[f*68 + tg*4];
      float4 b0= *(float4*)&rl[f*72 + cg*8];
      float4 b1= *(float4*)&rl[f*72 + cg*8 + 4];
      float av[4]={a.x,a.y,a.z,a.w};
      float bvv[8]={b0.x,b0.y,b0.z,b0.w,b1.x,b1.y,b1.z,b1.w};
      for(int i=0;i<4;i++)for(int j=0;j<8;j++) acc[i][j] += av[i]*bvv[j];
    }
    for(int tt=0;tt<4;tt++){
      float bv=-3.4e38f; int bi=0x7fffffff;
      for(int cc=0;cc<8;cc++){
        int i=cg*8+cc;
        if(i>=65) break;
        float r=acc[tt][cc];
        float cv; int ci;
        if(r >= -r){ cv=r; ci=i; } else { cv=-r; ci=i+65; }
        if(cv>bv || (cv==bv && ci<bi)){ bv=cv; bi=ci; }
      }
      pv[(tg*4+tt)*9+cg]=bv; pi[(tg*4+tt)*9+cg]=bi;
    }
  }
  __syncthreads();
  if(tid<64){
    int tg=t0+tid;
    if(tg<TPAD){
      float bv=pv[tid*9]; int bi=pi[tid*9];
      for(int cg=1;cg<9;cg++){
        float ov=pv[tid*9+cg]; int oi=pi[tid*9+cg];
        if(ov>bv || (ov==bv && oi<bi)){ bv=ov; bi=oi; }
      }
      buckets[((size_t)bh*4 + h)*TPAD + tg]=(unsigned char)bi;
    }
  }
}

// ---------------- stable counting sort == jnp.argsort(bucket*t+pos) ---------
__global__ __launch_bounds__(64) void k_sort(const unsigned char* __restrict__ buckets,
    unsigned short* __restrict__ sticker, unsigned short* __restrict__ undo){
  __shared__ int cnt[520];
  __shared__ int offs[520];
  int bh=blockIdx.x, tid=threadIdx.x;
  const unsigned char* bb = buckets + (size_t)bh*4*TPAD;
  for(int i=tid;i<520;i+=64) cnt[i]=0;
  __syncthreads();
  for(int i=tid;i<2080;i+=64){
    int h=i/TPAD;
    atomicAdd(&cnt[(int)bb[i]+h*NB_],1);
  }
  __syncthreads();
  if(tid==0){ int s=0; for(int k2=0;k2<520;k2++){ offs[k2]=s; s+=cnt[k2]; } }
  __syncthreads();
  if(tid<4){
    int h=tid;
    unsigned short* stk = sticker + (size_t)bh*2080;
    unsigned short* ud  = undo    + (size_t)bh*2080;
    for(int p=0;p<TPAD;p++){
      int key = (int)bb[h*TPAD+p] + h*NB_;
      int j = offs[key]++;
      stk[j] = (unsigned short)(h*TPAD+p);
      ud[h*TPAD+p] = (unsigned short)j;
    }
  }
}

// ---------------- attention pass 1: per-chunk LSE ---------------------------
__global__ __launch_bounds__(256) void k_attn1(const float* __restrict__ qk,
    const unsigned short* __restrict__ sticker, float* __restrict__ lse){
  __shared__ float rows[8][8][65];
  __shared__ int   sts[8][8];
  __shared__ float n2s[8][8];
  int tid=threadIdx.x, grp=tid>>5, lane=tid&31;
  int gid=blockIdx.x*8+grp;
  int bh=gid/NCH_, c=gid-bh*NCH_;
  int b=bh>>3, hd=bh&7;
  const unsigned short* stk = sticker + (size_t)bh*2080;
  if(lane<8){
    int r=lane;
    int cprev=(c+NCH_-1)%NCH_;
    int j=(r<4)? c*4+r : cprev*4+(r-4);
    sts[grp][r]=(int)stk[j]%TPAD;
  }
  __syncthreads();
  for(int idx=lane; idx<512; idx+=32){
    int r=idx>>6, f=idx&63;
    rows[grp][r][f]=qk[((size_t)b*TPAD+sts[grp][r])*(size_t)D_+hd*64+f];
  }
  __syncthreads();
  {
    int r=lane>>2, part=lane&3;
    float s=0.f;
    for(int f=part*16; f<part*16+16; f++){ float v=rows[grp][r][f]; s+=v*v; }
    s+=__shfl_xor(s,1,64); s+=__shfl_xor(s,2,64);
    if(part==0) n2s[grp][r]=s;
  }
  __syncthreads();
  int qi=lane>>3, kj=lane&7;
  float dt=0.f;
  for(int f=0;f<64;f++) dt += rows[grp][qi][f]*rows[grp][kj][f];
  float kn=n2s[grp][kj]; kn = kn>1e-24f? kn:1e-24f;
  dt = dt/sqrtf(kn)*0.125f;
  if(sts[grp][qi]==sts[grp][kj]) dt=-5e4f;
  float mx=dt;
  for(int o=1;o<8;o<<=1){ float om=__shfl_xor(mx,o,64); mx=om>mx?om:mx; }
  float sm=expf(dt-mx);
  for(int o=1;o<8;o<<=1) sm+=__shfl_xor(sm,o,64);
  if(kj==0) lse[(size_t)bh*2080 + c*4 + qi] = mx + logf(sm);
}

// ---------------- attention pass 2: probs with hash-round weight ------------
__global__ __launch_bounds__(256) void k_probs(const float* __restrict__ qk,
    const unsigned short* __restrict__ sticker, const unsigned short* __restrict__ undo,
    const float* __restrict__ lse, float* __restrict__ PR){
  __shared__ float rows[8][8][65];
  __shared__ int   sts[8][8];
  __shared__ float n2s[8][8];
  __shared__ float wq[8][4];
  int tid=threadIdx.x, grp=tid>>5, lane=tid&31;
  int gid=blockIdx.x*8+grp;
  int bh=gid/NCH_, c=gid-bh*NCH_;
  int b=bh>>3, hd=bh&7;
  const unsigned short* stk = sticker + (size_t)bh*2080;
  if(lane<8){
    int r=lane;
    int cprev=(c+NCH_-1)%NCH_;
    int j=(r<4)? c*4+r : cprev*4+(r-4);
    sts[grp][r]=(int)stk[j]%TPAD;
  }
  __syncthreads();
  for(int idx=lane; idx<512; idx+=32){
    int r=idx>>6, f=idx&63;
    rows[grp][r][f]=qk[((size_t)b*TPAD+sts[grp][r])*(size_t)D_+hd*64+f];
  }
  __syncthreads();
  {
    int r=lane>>2, part=lane&3;
    float s=0.f;
    for(int f=part*16; f<part*16+16; f++){ float v=rows[grp][r][f]; s+=v*v; }
    s+=__shfl_xor(s,1,64); s+=__shfl_xor(s,2,64);
    if(part==0) n2s[grp][r]=s;
  }
  __syncthreads();
  int qi=lane>>3, kj=lane&7;
  float dt=0.f;
  for(int f=0;f<64;f++) dt += rows[grp][qi][f]*rows[grp][kj][f];
  float kn=n2s[grp][kj]; kn = kn>1e-24f? kn:1e-24f;
  dt = dt/sqrtf(kn)*0.125f;
  if(sts[grp][qi]==sts[grp][kj]) dt=-5e4f;
  float L = lse[(size_t)bh*2080 + c*4 + qi];
  if(kj==0){
    int p = sts[grp][qi];
    const unsigned short* ud = undo + (size_t)bh*2080;
    const float* ls = lse + (size_t)bh*2080;
    float l0=ls[ud[p]],        l1=ls[ud[TPAD+p]];
    float l2=ls[ud[2*TPAD+p]], l3=ls[ud[3*TPAD+p]];
    float mx2=fmaxf(fmaxf(l0,l1),fmaxf(l2,l3));
    float s=expf(l0-mx2)+expf(l1-mx2)+expf(l2-mx2)+expf(l3-mx2);
    wq[grp][qi]=expf(L-mx2)/s;
  }
  __syncthreads();
  PR[((size_t)bh*2080 + c*4 + qi)*8 + kj] = expf(dt-L)*wq[grp][qi];
}

// ------- attention gather: out[b,t,:] = sum P*v, split-write hi/lo ----------
__global__ __launch_bounds__(256) void k_gather(const float* __restrict__ v,
    const unsigned short* __restrict__ sticker, const unsigned short* __restrict__ undo,
    const float* __restrict__ PR, unsigned short* __restrict__ ahi,
    unsigned short* __restrict__ alo){
  __shared__ int   ridx[8][32];
  __shared__ float pval[8][32];
  int b=blockIdx.x, t=blockIdx.y;
  int tid=threadIdx.x, hd=tid>>5, l=tid&31;
  int bh=b*8+hd;
  const unsigned short* stk = sticker + (size_t)bh*2080;
  const unsigned short* ud  = undo    + (size_t)bh*2080;
  {
    int h=l>>3, kj=l&7;
    int j = (int)ud[h*TPAD+t];
    int c = j>>2;
    int slot = (kj<4)? (c*4+kj) : (((c+NCH_-1)%NCH_)*4 + (kj-4));
    ridx[hd][l] = (int)stk[slot]%TPAD;
    pval[hd][l] = PR[((size_t)bh*2080 + j)*8 + kj];
  }
  __syncthreads();
  int f0=l*2;
  float a0=0.f, a1=0.f;
  const float* vb = v + (size_t)b*TPAD*D_ + hd*64 + f0;
  for(int i=0;i<32;i++){
    const float* vr = vb + (size_t)ridx[hd][i]*D_;
    float p=pval[hd][i];
    a0 += p*vr[0];
    a1 += p*vr[1];
  }
  size_t off = ((size_t)b*NTOK + t)*(size_t)D_ + hd*64 + f0;
  unsigned short h0=f2bf(a0), h1=f2bf(a1);
  ahi[off]=h0; ahi[off+1]=h1;
  alo[off]=f2bf(a0-bf2f(h0)); alo[off+1]=f2bf(a1-bf2f(h1));
}

// -------- x = LN(x + delta)*g + b ; also split-write hi/lo ------------------
__global__ __launch_bounds__(256) void k_addln(float* __restrict__ x,
    const float* __restrict__ delta, const float* __restrict__ g,
    const float* __restrict__ bb, unsigned short* __restrict__ xhi,
    unsigned short* __restrict__ xlo){
  __shared__ float red[4];
  int row=blockIdx.x, tid=threadIdx.x;
  size_t base=(size_t)row*D_;
  float v0=x[base+tid]+delta[base+tid];
  float v1=x[base+tid+256]+delta[base+tid+256];
  float m=blockReduce256(v0+v1,red,tid)*(1.f/512.f);
  float d0=v0-m, d1=v1-m;
  float var=blockReduce256(d0*d0+d1*d1,red,tid)*(1.f/512.f);
  float inv=1.f/sqrtf(var+1e-5f);
  float y0=d0*inv*g[tid]    +bb[tid];
  float y1=d1*inv*g[tid+256]+bb[tid+256];
  x[base+tid]=y0; x[base+tid+256]=y1;
  unsigned short h0=f2bf(y0), h1=f2bf(y1);
  xhi[base+tid]=h0; xhi[base+tid+256]=h1;
  xlo[base+tid]=f2bf(y0-bf2f(h0)); xlo[base+tid+256]=f2bf(y1-bf2f(h1));
}

// ---------------- final LN on last token + projection -----------------------
__global__ __launch_bounds__(256) void k_dec(const float* __restrict__ x,
    const float* __restrict__ gF, const float* __restrict__ bF,
    const float* __restrict__ Wp, const float* __restrict__ bp,
    float* __restrict__ dec){
  __shared__ float red[4];
  int b=blockIdx.x, tid=threadIdx.x;
  const float* row = x + ((size_t)b*NTOK + (NTOK-1))*(size_t)D_;
  float v0=row[tid], v1=row[tid+256];
  float m=blockReduce256(v0+v1,red,tid)*(1.f/512.f);
  float d0=v0-m, d1=v1-m;
  float var=blockReduce256(d0*d0+d1*d1,red,tid)*(1.f/512.f);
  float inv=1.f/sqrtf(var+1e-5f);
  float y0=d0*inv*gF[tid]    +bF[tid];
  float y1=d1*inv*gF[tid+256]+bF[tid+256];
  float dd=blockReduce256(y0*Wp[tid]+y1*Wp[tid+256],red,tid);
  if(tid==0) dec[b]=dd+bp[0];
}

__global__ void k_out(const float* __restrict__ dec, const float* __restrict__ means,
    const float* __restrict__ stdev, float* __restrict__ out){
  int idx=blockIdx.x*256+threadIdx.x;
  int e=idx&511, j=(idx>>9)&31, i=idx>>14;
  out[idx]=dec[j]*stdev[i*E_+e]+means[i*E_+e];
}

// ============================================================================
extern "C" void kernel_launch(void* const* d_in, const int* in_sizes, int n_in,
                              void* d_out, int out_size, void* d_ws, size_t ws_size,
                              hipStream_t stream){
  (void)in_sizes; (void)n_in; (void)out_size; (void)ws_size;
  const float* xe   = (const float*)d_in[0];
  const float* xm   = (const float*)d_in[1];
  const float* Wemb = (const float*)d_in[2];
  const float* bemb = (const float*)d_in[3];
  const float* Wqk  = (const float*)d_in[4];
  const float* Wv   = (const float*)d_in[5];
  const float* Wo   = (const float*)d_in[6];
  const float* boP  = (const float*)d_in[7];
  const float* Wc1  = (const float*)d_in[8];
  const float* bc1  = (const float*)d_in[9];
  const float* Wc2  = (const float*)d_in[10];
  const float* bc2  = (const float*)d_in[11];
  const float* g1   = (const float*)d_in[12];
  const float* b1   = (const float*)d_in[13];
  const float* g2   = (const float*)d_in[14];
  const float* b2   = (const float*)d_in[15];
  const float* gF   = (const float*)d_in[16];
  const float* bF   = (const float*)d_in[17];
  const float* Wp   = (const float*)d_in[18];
  const float* bp   = (const float*)d_in[19];
  const float* rot  = (const float*)d_in[20];
  float* out = (float*)d_out;

  // ---- workspace carve (~171 MB; R1 ran 181 MB fine) ----
  char* w=(char*)d_ws;
  auto carve=[&](size_t n)->char*{ char* p=w; w += (n+255)&~(size_t)255; return p; };
  float* means=(float*)carve(65536);
  float* stdev=(float*)carve(65536);
  float* dec  =(float*)carve(256);
  float* x    =(float*)carve((size_t)B_*NTOK*D_*4);           // 33.8 MB
  unsigned short* xhi=(unsigned short*)carve((size_t)B_*NTOK*D_*2); // 16.9
  unsigned short* xlo=(unsigned short*)carve((size_t)B_*NTOK*D_*2); // 16.9
  float* BIG  =(float*)carve((size_t)B_*TPAD*D_*4);           // 34.1 (qk/v/delta)
  unsigned short* hidHi=(unsigned short*)carve((size_t)2816*DFF_*2); // 11.5
  unsigned short* hidLo=(unsigned short*)carve((size_t)2816*DFF_*2); // 11.5
  constexpr size_t WTOT=6029312;
  unsigned short* whi=(unsigned short*)carve(WTOT*2);         // 12.1
  unsigned short* wlo=(unsigned short*)carve(WTOT*2);         // 12.1
  float* PR   =(float*)carve((size_t)BH_*2080*8*4);           // 17.0
  unsigned char*  bkt=(unsigned char*) carve((size_t)BH_*4*TPAD);
  unsigned short* stk=(unsigned short*)carve((size_t)BH_*2080*2);
  unsigned short* ud =(unsigned short*)carve((size_t)BH_*2080*2);
  float* lseB =(float*)carve((size_t)BH_*2080*4);

  // weight arena offsets (elements). TOTAL element counts:
  // Wemb 262144; Wqk/Wv/Wo 524288 each (2 layers); Wc1/Wc2 2097152 each (2 layers).
  constexpr size_t oWemb=0, oWqk=262144, oWv=786432, oWo=1310720,
                   oWc1=1835008, oWc2=3932160;
  constexpr size_t Wsz=262144;          // per-layer D*D
  constexpr size_t C1sz=1048576;        // per-layer DFF*D
  constexpr size_t C2sz=1048576;        // per-layer D*DFF

  // ---- split weights once (n = TOTAL element count of each tensor) ----
  k_split<<<(262144+255)/256,256,0,stream>>>(Wemb,whi+oWemb,wlo+oWemb,262144);
  k_split<<<(524288+255)/256,256,0,stream>>>(Wqk, whi+oWqk, wlo+oWqk, 524288);
  k_split<<<(524288+255)/256,256,0,stream>>>(Wv,  whi+oWv,  wlo+oWv,  524288);
  k_split<<<(524288+255)/256,256,0,stream>>>(Wo,  whi+oWo,  wlo+oWo,  524288);
  k_split<<<(2097152+255)/256,256,0,stream>>>(Wc1, whi+oWc1, wlo+oWc1, 2097152);
  k_split<<<(2097152+255)/256,256,0,stream>>>(Wc2, whi+oWc2, wlo+oWc2, 2097152);

  // ---- embedding ----
  k_revin<<<dim3(2,B_),256,0,stream>>>(xe,means,stdev);
  k_pack_tok<<<dim3(8,8,B_),256,0,stream>>>(xe,means,stdev,xhi,xlo);
  k_pack_marks<<<(B_*NMARK_*L_)/256,256,0,stream>>>(xm,xhi,xlo);
  k_gemm<0,false><<<dim3(4,129),256,0,stream>>>(xhi,xlo,whi+oWemb,wlo+oWemb,bemb,x,nullptr,nullptr,16512,512,512);
  k_split<<<(B_*NTOK*D_+255)/256,256,0,stream>>>(x,xhi,xlo,B_*NTOK*D_);

  const int chunkBlocks[6]={22,22,22,21,21,21};

  for(int l=0;l<NLAYERS_;l++){
    const unsigned short* Wqk_h=whi+oWqk+(size_t)l*Wsz, *Wqk_l2=wlo+oWqk+(size_t)l*Wsz;
    const unsigned short* Wv_h =whi+oWv +(size_t)l*Wsz, *Wv_l2 =wlo+oWv +(size_t)l*Wsz;
    const unsigned short* Wo_h =whi+oWo +(size_t)l*Wsz, *Wo_l2 =wlo+oWo +(size_t)l*Wsz;
    const unsigned short* Wc1_h=whi+oWc1+(size_t)l*C1sz,*Wc1_l2=wlo+oWc1+(size_t)l*C1sz;
    const unsigned short* Wc2_h=whi+oWc2+(size_t)l*C2sz,*Wc2_l2=wlo+oWc2+(size_t)l*C2sz;
    const float* bo_l =boP+(size_t)l*D_;
    const float* bc1_l=bc1+(size_t)l*DFF_;
    const float* bc2_l=bc2+(size_t)l*D_;
    const float* g1_l=g1+(size_t)l*D_;
    const float* b1_l=b1+(size_t)l*D_;
    const float* g2_l=g2+(size_t)l*D_;
    const float* b2_l=b2+(size_t)l*D_;
    const float* rot_l=rot+(size_t)l*DH_*NHASH_*(NB_/2);

    // qk projection
    k_gemm<0,true><<<dim3(4,130),256,0,stream>>>(xhi,xlo,Wqk_h,Wqk_l2,nullptr,BIG,nullptr,nullptr,16640,512,512);
    // LSH routing (tiled GEMM+argmax) + exact stable sort
    k_buckets<<<dim3(BH_,NHASH_,9),128,0,stream>>>(BIG,rot_l,bkt);
    k_sort<<<BH_,64,0,stream>>>(bkt,stk,ud);
    // LSE + probs (qk consumed after)
    k_attn1<<<16640,256,0,stream>>>(BIG,stk,lseB);
    k_probs<<<16640,256,0,stream>>>(BIG,stk,ud,lseB,PR);
    // v projection overwrites qk; gather split-writes attn into xhi/xlo
    k_gemm<0,true><<<dim3(4,130),256,0,stream>>>(xhi,xlo,Wv_h,Wv_l2,nullptr,BIG,nullptr,nullptr,16640,512,512);
    k_gather<<<dim3(B_,NTOK),256,0,stream>>>(BIG,stk,ud,PR,xhi,xlo);
    // output projection + residual LN (re-splits x)
    k_gemm<0,false><<<dim3(4,129),256,0,stream>>>(xhi,xlo,Wo_h,Wo_l2,bo_l,BIG,nullptr,nullptr,16512,512,512);
    k_addln<<<16512,256,0,stream>>>(x,BIG,g1_l,b1_l,xhi,xlo);
    // FFN, row-chunked; hidden written directly as hi/lo bf16
    int rs=0;
    for(int ch=0; ch<6; ch++){
      int nb=chunkBlocks[ch];
      int rows=nb*128;
      k_gemm<1,false><<<dim3(16,nb),256,0,stream>>>(xhi+(size_t)rs*D_,xlo+(size_t)rs*D_,Wc1_h,Wc1_l2,bc1_l,nullptr,hidHi,hidLo,rows,2048,512);
      k_gemm<0,false><<<dim3(4,nb),256,0,stream>>>(hidHi,hidLo,Wc2_h,Wc2_l2,bc2_l,BIG+(size_t)rs*D_,nullptr,nullptr,rows,512,2048);
      rs+=rows;
    }
    k_addln<<<16512,256,0,stream>>>(x,BIG,g2_l,b2_l,xhi,xlo);
  }

  k_dec<<<B_,256,0,stream>>>(x,gF,bF,Wp,bp,dec);
  k_out<<<2048,256,0,stream>>>(dec,means,stdev,out);
}

// Round 7
// 1928.276 us; speedup vs baseline: 2.1774x; 1.6078x over previous
//
#include <hip/hip_runtime.h>
#include <stdint.h>

// ============================================================================
// Reformer/LSH iTransformer forward on MI355X (gfx950). ALL I/O FP32.
// R7 = R6 with the embed-GEMM in-place alias race fixed: embed writes x only
// (OUTMODE 0), then k_split(x -> xhi/xlo). All kernels are now alias-free ->
// deterministic across graph replays. GEMMs: global_load_lds staging,
// 3 bf16 MFMAs/K-step on pre-split hi/lo operands (bit-identical math chain).
// ============================================================================

constexpr int B_=32, L_=512, E_=512, NMARK_=4, D_=512, DFF_=2048, NLAYERS_=2;
constexpr int NTOK=516, TPAD=520, DH_=64, NB_=130, NHASH_=4;
constexpr int BH_=256, NCH_=520;

typedef __attribute__((ext_vector_type(8))) short v8s;
typedef __attribute__((ext_vector_type(4))) float v4f;

typedef __attribute__((address_space(1))) const unsigned int gu32;
typedef __attribute__((address_space(3))) unsigned int lu32;
static __device__ __forceinline__ void gload_lds16(const void* g, void* l){
  __builtin_amdgcn_global_load_lds((gu32*)g, (lu32*)l, 16, 0, 0);
}

static __device__ __forceinline__ unsigned short f2bf(float f){
  union{float f; unsigned int u;} c; c.f=f;
  unsigned int u=c.u;
  return (unsigned short)((u + 0x7fffu + ((u>>16)&1u))>>16);  // RNE
}
static __device__ __forceinline__ float bf2f(unsigned short h){
  union{unsigned int u; float f;} c; c.u=((unsigned int)h)<<16; return c.f;
}
static __device__ __forceinline__ float blockReduce256(float v, float* red, int tid){
  for(int o=32;o;o>>=1) v += __shfl_down(v,o,64);
  __syncthreads();
  if((tid&63)==0) red[tid>>6]=v;
  __syncthreads();
  return red[0]+red[1]+red[2]+red[3];
}

// ---------------- generic fp32 -> (hi,lo) bf16 split ------------------------
__global__ void k_split(const float* __restrict__ src, unsigned short* __restrict__ hi,
    unsigned short* __restrict__ lo, int n){
  int idx=blockIdx.x*256+threadIdx.x;
  if(idx>=n) return;
  float v=src[idx];
  unsigned short h=f2bf(v);
  hi[idx]=h; lo[idx]=f2bf(v-bf2f(h));
}

// ---------------- RevIN stats over L per (b,e) ------------------------------
__global__ __launch_bounds__(256) void k_revin(const float* __restrict__ xe,
    float* __restrict__ means, float* __restrict__ stdev){
  int b=blockIdx.y;
  int e=blockIdx.x*256+threadIdx.x;
  const float* p = xe + (size_t)b*L_*E_ + e;
  float s=0.f,s2=0.f;
  for(int l=0;l<L_;l++){ float v=p[(size_t)l*E_]; s+=v; s2+=v*v; }
  float m=s*(1.f/512.f);
  float var=s2*(1.f/512.f)-m*m;
  var = var>0.f? var:0.f;
  means[b*E_+e]=m;
  stdev[b*E_+e]=sqrtf(var+1e-5f);
}

// ------- transpose x_enc -> token rows with RevIN, split-write hi/lo --------
__global__ __launch_bounds__(256) void k_pack_tok(const float* __restrict__ xe,
     const float* __restrict__ means, const float* __restrict__ stdev,
     unsigned short* __restrict__ hi, unsigned short* __restrict__ lo){
  __shared__ float tile[64][65];
  int b=blockIdx.z;
  int ct=blockIdx.x*64, lt=blockIdx.y*64;
  int tid=threadIdx.x;
  int i=tid>>2, j0=(tid&3)*16;
  {
    const float* src = xe + ((size_t)b*L_ + lt + i)*E_ + ct + j0;
    float tmp[16];
    *(float4*)&tmp[0]  = *(const float4*)(src);
    *(float4*)&tmp[4]  = *(const float4*)(src+4);
    *(float4*)&tmp[8]  = *(const float4*)(src+8);
    *(float4*)&tmp[12] = *(const float4*)(src+12);
    for(int j=0;j<16;j++) tile[i][j0+j]=tmp[j];
  }
  __syncthreads();
  {
    float ms=means[b*E_+ct+i];
    float sd=stdev[b*E_+ct+i];
    unsigned short hs[16], ls[16];
    for(int j=0;j<16;j++){
      float v=(tile[j0+j][i]-ms)/sd;
      unsigned short hh=f2bf(v);
      hs[j]=hh; ls[j]=f2bf(v-bf2f(hh));
    }
    size_t off = ((size_t)b*NTOK + ct + i)*(size_t)L_ + lt + j0;
    *(uint4*)&hi[off]   = *(uint4*)&hs[0];
    *(uint4*)&hi[off+8] = *(uint4*)&hs[8];
    *(uint4*)&lo[off]   = *(uint4*)&ls[0];
    *(uint4*)&lo[off+8] = *(uint4*)&ls[8];
  }
}

__global__ void k_pack_marks(const float* __restrict__ xm,
    unsigned short* __restrict__ hi, unsigned short* __restrict__ lo){
  int idx=blockIdx.x*256+threadIdx.x; // 32*4*512
  int l=idx&511, j=(idx>>9)&3, b=idx>>11;
  float v = xm[((size_t)b*L_ + l)*NMARK_ + j];
  unsigned short hh=f2bf(v);
  size_t off=((size_t)b*NTOK + E_ + j)*(size_t)L_ + l;
  hi[off]=hh; lo[off]=f2bf(v-bf2f(hh));
}

// ---------------- 128x128 bf16 MFMA GEMM, global_load_lds staging -----------
// C = (Ahi+Alo)@(Bhi+Blo)^T + bias, 3 MFMAs (AloBhi + AhiBlo + AhiBhi).
// OUTMODE 0: fp32 C. 1: relu + split hi/lo.  (no in-place alias modes!)
// TPADDED: M rows indexed b*520+t, A from compact [b*516+t], t>=516 -> zeropad.
template<int OUTMODE, bool TPADDED>
__global__ __launch_bounds__(256) void k_gemm(
    const unsigned short* __restrict__ Ahi, const unsigned short* __restrict__ Alo,
    const unsigned short* __restrict__ Bhi, const unsigned short* __restrict__ Blo,
    const float* __restrict__ bias, float* __restrict__ Cf,
    unsigned short* __restrict__ Chi, unsigned short* __restrict__ Clo,
    const unsigned short* __restrict__ zeropad,
    int M, int N, int K)
{
  __shared__ __align__(16) unsigned short As[128*32];
  __shared__ __align__(16) unsigned short Al[128*32];
  __shared__ __align__(16) unsigned short Bs[128*32];
  __shared__ __align__(16) unsigned short Bl[128*32];
  const int m0=blockIdx.y*128, n0=blockIdx.x*128;
  const int tid=threadIdx.x, lane=tid&63, wave=tid>>6;
  const int wm=(wave>>1)*64, wn=(wave&1)*64;

  // wave w DMAs tile w; call j covers rows j*16..j*16+15;
  // lane i -> row j*16 + (i>>2), 16B seg (i&3). LDS dst = tile + j*1024B.
  const unsigned short* srcp = (wave==0)?Ahi:(wave==1)?Alo:(wave==2)?Bhi:Blo;
  unsigned short* dstp = (wave==0)?As:(wave==1)?Al:(wave==2)?Bs:Bl;
  const int rsub=lane>>2, seg=(lane&3)*8;
  const unsigned short* gp[8]; int stp[8];
  #pragma unroll
  for(int j=0;j<8;j++){
    int row=j*16+rsub;
    if(wave<2){
      size_t ao; bool valid=true;
      int g=m0+row;
      if constexpr (TPADDED){
        int b=g/TPAD; int t=g-b*TPAD; valid=(t<NTOK);
        ao=((size_t)b*NTOK + (valid?t:0))*(size_t)K;
      } else ao=(size_t)g*(size_t)K;
      gp[j]= valid ? (srcp+ao+seg) : (zeropad+seg);
      stp[j]= valid ? 32 : 0;
    } else {
      gp[j]= srcp + (size_t)(n0+row)*(size_t)K + seg;
      stp[j]=32;
    }
  }

  v4f acc[4][4];
  for(int i=0;i<4;i++)for(int j=0;j<4;j++) acc[i][j]=(v4f){0.f,0.f,0.f,0.f};
  const int am = wm + (lane&15);
  const int bn = wn + (lane&15);
  const int kk = (lane>>4)*8;
  for(int k0=0;k0<K;k0+=32){
    __syncthreads();
    #pragma unroll
    for(int j=0;j<8;j++){
      gload_lds16(gp[j], dstp + j*512);
      gp[j]+=stp[j];
    }
    __syncthreads();
    v8s a[4], al[4], b[4], bl[4];
    for(int t=0;t<4;t++){
      a[t] =*(const v8s*)&As[(am+t*16)*32+kk];
      al[t]=*(const v8s*)&Al[(am+t*16)*32+kk];
      b[t] =*(const v8s*)&Bs[(bn+t*16)*32+kk];
      bl[t]=*(const v8s*)&Bl[(bn+t*16)*32+kk];
    }
    for(int mt=0;mt<4;mt++)for(int nt=0;nt<4;nt++){
      acc[mt][nt]=__builtin_amdgcn_mfma_f32_16x16x32_bf16(al[mt],b[nt], acc[mt][nt],0,0,0);
      acc[mt][nt]=__builtin_amdgcn_mfma_f32_16x16x32_bf16(a[mt], bl[nt],acc[mt][nt],0,0,0);
      acc[mt][nt]=__builtin_amdgcn_mfma_f32_16x16x32_bf16(a[mt], b[nt], acc[mt][nt],0,0,0);
    }
  }
  // C/D mapping: col=lane&15, row=(lane>>4)*4+r
  for(int mt=0;mt<4;mt++)for(int nt=0;nt<4;nt++){
    int col = n0 + wn + nt*16 + (lane&15);
    int rb  = m0 + wm + mt*16 + (lane>>4)*4;
    float bv = bias ? bias[col] : 0.f;
    for(int r=0;r<4;r++){
      float v = acc[mt][nt][r] + bv;
      size_t off=(size_t)(rb+r)*N + col;
      if constexpr (OUTMODE==0){
        Cf[off]=v;
      } else {
        v = v>0.f ? v : 0.f;
        unsigned short hh=f2bf(v);
        Chi[off]=hh; Clo[off]=f2bf(v-bf2f(hh));
      }
    }
  }
}

// ---------------- LSH buckets: wave=hash, thread=token, rot via s_load ------
__global__ __launch_bounds__(256) void k_buckets(const float* __restrict__ qk,
    const float* __restrict__ rot, unsigned char* __restrict__ buckets){
  __shared__ float qkT[64*69];   // [f][t], stride 69 -> conflict-free reads
  int bh=blockIdx.x, tc=blockIdx.y;
  int b=bh>>3, hd=bh&7;
  int t0=tc*64;
  int tid=threadIdx.x;
  for(int j=tid;j<4096;j+=256){
    int t=j>>6, f=j&63;
    int tg=t0+t;
    qkT[f*69+t] = (tg<TPAD)? qk[((size_t)b*TPAD+tg)*(size_t)D_ + hd*64 + f] : 0.f;
  }
  __syncthreads();
  int h = __builtin_amdgcn_readfirstlane(tid>>6);   // wave-uniform hash
  int t = tid&63;
  const float* rh = rot + h*65;                     // rot[f][4][65]
  float acc[65];
  #pragma unroll
  for(int i=0;i<65;i++) acc[i]=0.f;
  for(int f=0;f<64;f++){
    float q = qkT[f*69+t];
    #pragma unroll
    for(int i=0;i<65;i++) acc[i] += q * rh[f*260+i];  // rh uniform -> s_load
  }
  float bv=-3.4e38f; int bi=0x7fffffff;
  #pragma unroll
  for(int i=0;i<65;i++){
    float r=acc[i]; float cv; int ci;
    if(r>=-r){cv=r;ci=i;}else{cv=-r;ci=i+65;}
    if(cv>bv||(cv==bv&&ci<bi)){bv=cv;bi=ci;}
  }
  int tg=t0+t;
  if(tg<TPAD) buckets[((size_t)bh*4+h)*TPAD+tg]=(unsigned char)bi;
}

// ---------------- stable counting sort == jnp.argsort(bucket*t+pos) ---------
__global__ __launch_bounds__(64) void k_sort(const unsigned char* __restrict__ buckets,
    unsigned short* __restrict__ sticker, unsigned short* __restrict__ undo){
  __shared__ int cnt[520];
  __shared__ int offs[520];
  int bh=blockIdx.x, tid=threadIdx.x;
  const unsigned char* bb = buckets + (size_t)bh*4*TPAD;
  for(int i=tid;i<520;i+=64) cnt[i]=0;
  __syncthreads();
  for(int i=tid;i<2080;i+=64){
    int h=i/TPAD;
    atomicAdd(&cnt[(int)bb[i]+h*NB_],1);
  }
  __syncthreads();
  if(tid==0){ int s=0; for(int k2=0;k2<520;k2++){ offs[k2]=s; s+=cnt[k2]; } }
  __syncthreads();
  if(tid<4){
    int h=tid;
    unsigned short* stk = sticker + (size_t)bh*2080;
    unsigned short* ud  = undo    + (size_t)bh*2080;
    for(int p=0;p<TPAD;p++){
      int key = (int)bb[h*TPAD+p] + h*NB_;
      int j = offs[key]++;
      stk[j] = (unsigned short)(h*TPAD+p);
      ud[h*TPAD+p] = (unsigned short)j;
    }
  }
}

// -------- attention pass 1: per-chunk LSE + store masked dots into PR -------
__global__ __launch_bounds__(256) void k_attn1(const float* __restrict__ qk,
    const unsigned short* __restrict__ sticker, float* __restrict__ lse,
    float* __restrict__ PR){
  __shared__ float rows[8][8][68];
  __shared__ int   sts[8][8];
  __shared__ float n2s[8][8];
  int tid=threadIdx.x, grp=tid>>5, lane=tid&31;
  int gid=blockIdx.x*8+grp;
  int bh=gid/NCH_, c=gid-bh*NCH_;
  int b=bh>>3, hd=bh&7;
  const unsigned short* stk = sticker + (size_t)bh*2080;
  if(lane<8){
    int r=lane;
    int cprev=(c+NCH_-1)%NCH_;
    int j=(r<4)? c*4+r : cprev*4+(r-4);
    sts[grp][r]=(int)stk[j]%TPAD;
  }
  __syncthreads();
  #pragma unroll
  for(int it=0; it<2; it++){
    int j=lane+32*it;
    int r=j>>3, f0=(j&7)*8;
    const float* src=qk+((size_t)b*TPAD+sts[grp][r])*(size_t)D_+hd*64+f0;
    *(float4*)&rows[grp][r][f0]   = *(const float4*)src;
    *(float4*)&rows[grp][r][f0+4] = *(const float4*)(src+4);
  }
  __syncthreads();
  {
    int r=lane>>2, part=lane&3;
    float s=0.f;
    #pragma unroll
    for(int f=part*16; f<part*16+16; f++){ float v=rows[grp][r][f]; s+=v*v; }
    s+=__shfl_xor(s,1,64); s+=__shfl_xor(s,2,64);
    if(part==0) n2s[grp][r]=s;
  }
  __syncthreads();
  int qi=lane>>3, kj=lane&7;
  float dt=0.f;
  #pragma unroll
  for(int f=0;f<64;f++) dt += rows[grp][qi][f]*rows[grp][kj][f];
  float kn=n2s[grp][kj]; kn = kn>1e-24f? kn:1e-24f;
  dt = dt/sqrtf(kn)*0.125f;
  if(sts[grp][qi]==sts[grp][kj]) dt=-5e4f;
  PR[((size_t)bh*2080 + c*4 + qi)*8 + kj] = dt;
  float mx=dt;
  for(int o=1;o<8;o<<=1){ float om=__shfl_xor(mx,o,64); mx=om>mx?om:mx; }
  float sm=expf(dt-mx);
  for(int o=1;o<8;o<<=1) sm+=__shfl_xor(sm,o,64);
  if(kj==0) lse[(size_t)bh*2080 + c*4 + qi] = mx + logf(sm);
}

// ---------------- per-token LSE over the 4 hash rounds ----------------------
__global__ void k_wlse(const float* __restrict__ lse, const unsigned short* __restrict__ undo,
    float* __restrict__ lsetok){
  int idx=blockIdx.x*256+threadIdx.x;   // BH*520
  if(idx>=BH_*TPAD) return;
  int bh=idx/TPAD, p=idx-bh*TPAD;
  const unsigned short* u=undo+(size_t)bh*2080;
  const float* ls=lse+(size_t)bh*2080;
  float l0=ls[u[p]], l1=ls[u[TPAD+p]], l2=ls[u[2*TPAD+p]], l3=ls[u[3*TPAD+p]];
  float mx=fmaxf(fmaxf(l0,l1),fmaxf(l2,l3));
  lsetok[idx]=mx+logf(expf(l0-mx)+expf(l1-mx)+expf(l2-mx)+expf(l3-mx));
}

// ---------------- dots -> probs (elementwise, in-place in PR) ---------------
__global__ void k_probs(const float* __restrict__ lse, const unsigned short* __restrict__ sticker,
    const float* __restrict__ lsetok, float* __restrict__ PR){
  int j=blockIdx.x*256+threadIdx.x;     // BH*2080 slots
  if(j>=BH_*2080) return;
  int bh=j/2080;
  float L=lse[j];
  int p=(int)sticker[j]%TPAD;
  float w=expf(L-lsetok[bh*TPAD+p]);
  float* pr=PR+(size_t)j*8;
  float4 d0=*(float4*)pr, d1=*(float4*)(pr+4);
  d0.x=expf(d0.x-L)*w; d0.y=expf(d0.y-L)*w; d0.z=expf(d0.z-L)*w; d0.w=expf(d0.w-L)*w;
  d1.x=expf(d1.x-L)*w; d1.y=expf(d1.y-L)*w; d1.z=expf(d1.z-L)*w; d1.w=expf(d1.w-L)*w;
  *(float4*)pr=d0; *(float4*)(pr+4)=d1;
}

// ------- attention gather: out[b,t,:] = sum P*v, split-write hi/lo ----------
__global__ __launch_bounds__(256) void k_gather(const float* __restrict__ v,
    const unsigned short* __restrict__ sticker, const unsigned short* __restrict__ undo,
    const float* __restrict__ PR, unsigned short* __restrict__ ahi,
    unsigned short* __restrict__ alo){
  __shared__ int   ridx[8][32];
  __shared__ float pval[8][32];
  int b=blockIdx.x, t=blockIdx.y;
  int tid=threadIdx.x, hd=tid>>5, l=tid&31;
  int bh=b*8+hd;
  const unsigned short* stk = sticker + (size_t)bh*2080;
  const unsigned short* ud  = undo    + (size_t)bh*2080;
  {
    int h=l>>3, kj=l&7;
    int j = (int)ud[h*TPAD+t];
    int c = j>>2;
    int slot = (kj<4)? (c*4+kj) : (((c+NCH_-1)%NCH_)*4 + (kj-4));
    ridx[hd][l] = (int)stk[slot]%TPAD;
    pval[hd][l] = PR[((size_t)bh*2080 + j)*8 + kj];
  }
  __syncthreads();
  int f0=l*2;
  float a0=0.f, a1=0.f;
  const float* vb = v + (size_t)b*TPAD*D_ + hd*64 + f0;
  for(int i=0;i<32;i++){
    const float* vr = vb + (size_t)ridx[hd][i]*D_;
    float p=pval[hd][i];
    a0 += p*vr[0];
    a1 += p*vr[1];
  }
  size_t off = ((size_t)b*NTOK + t)*(size_t)D_ + hd*64 + f0;
  unsigned short h0=f2bf(a0), h1=f2bf(a1);
  ahi[off]=h0; ahi[off+1]=h1;
  alo[off]=f2bf(a0-bf2f(h0)); alo[off+1]=f2bf(a1-bf2f(h1));
}

// -------- x = LN(x + delta)*g + b ; also split-write hi/lo ------------------
__global__ __launch_bounds__(256) void k_addln(float* __restrict__ x,
    const float* __restrict__ delta, const float* __restrict__ g,
    const float* __restrict__ bb, unsigned short* __restrict__ xhi,
    unsigned short* __restrict__ xlo){
  __shared__ float red[4];
  int row=blockIdx.x, tid=threadIdx.x;
  size_t base=(size_t)row*D_;
  float v0=x[base+tid]+delta[base+tid];
  float v1=x[base+tid+256]+delta[base+tid+256];
  float m=blockReduce256(v0+v1,red,tid)*(1.f/512.f);
  float d0=v0-m, d1=v1-m;
  float var=blockReduce256(d0*d0+d1*d1,red,tid)*(1.f/512.f);
  float inv=1.f/sqrtf(var+1e-5f);
  float y0=d0*inv*g[tid]    +bb[tid];
  float y1=d1*inv*g[tid+256]+bb[tid+256];
  x[base+tid]=y0; x[base+tid+256]=y1;
  unsigned short h0=f2bf(y0), h1=f2bf(y1);
  xhi[base+tid]=h0; xhi[base+tid+256]=h1;
  xlo[base+tid]=f2bf(y0-bf2f(h0)); xlo[base+tid+256]=f2bf(y1-bf2f(h1));
}

// ---------------- final LN on last token + projection -----------------------
__global__ __launch_bounds__(256) void k_dec(const float* __restrict__ x,
    const float* __restrict__ gF, const float* __restrict__ bF,
    const float* __restrict__ Wp, const float* __restrict__ bp,
    float* __restrict__ dec){
  __shared__ float red[4];
  int b=blockIdx.x, tid=threadIdx.x;
  const float* row = x + ((size_t)b*NTOK + (NTOK-1))*(size_t)D_;
  float v0=row[tid], v1=row[tid+256];
  float m=blockReduce256(v0+v1,red,tid)*(1.f/512.f);
  float d0=v0-m, d1=v1-m;
  float var=blockReduce256(d0*d0+d1*d1,red,tid)*(1.f/512.f);
  float inv=1.f/sqrtf(var+1e-5f);
  float y0=d0*inv*gF[tid]    +bF[tid];
  float y1=d1*inv*gF[tid+256]+bF[tid+256];
  float dd=blockReduce256(y0*Wp[tid]+y1*Wp[tid+256],red,tid);
  if(tid==0) dec[b]=dd+bp[0];
}

__global__ void k_out(const float* __restrict__ dec, const float* __restrict__ means,
    const float* __restrict__ stdev, float* __restrict__ out){
  int idx=blockIdx.x*256+threadIdx.x;
  int e=idx&511, j=(idx>>9)&31, i=idx>>14;
  out[idx]=dec[j]*stdev[i*E_+e]+means[i*E_+e];
}

// ============================================================================
extern "C" void kernel_launch(void* const* d_in, const int* in_sizes, int n_in,
                              void* d_out, int out_size, void* d_ws, size_t ws_size,
                              hipStream_t stream){
  (void)in_sizes; (void)n_in; (void)out_size; (void)ws_size;
  const float* xe   = (const float*)d_in[0];
  const float* xm   = (const float*)d_in[1];
  const float* Wemb = (const float*)d_in[2];
  const float* bemb = (const float*)d_in[3];
  const float* Wqk  = (const float*)d_in[4];
  const float* Wv   = (const float*)d_in[5];
  const float* Wo   = (const float*)d_in[6];
  const float* boP  = (const float*)d_in[7];
  const float* Wc1  = (const float*)d_in[8];
  const float* bc1  = (const float*)d_in[9];
  const float* Wc2  = (const float*)d_in[10];
  const float* bc2  = (const float*)d_in[11];
  const float* g1   = (const float*)d_in[12];
  const float* b1   = (const float*)d_in[13];
  const float* g2   = (const float*)d_in[14];
  const float* b2   = (const float*)d_in[15];
  const float* gF   = (const float*)d_in[16];
  const float* bF   = (const float*)d_in[17];
  const float* Wp   = (const float*)d_in[18];
  const float* bp   = (const float*)d_in[19];
  const float* rot  = (const float*)d_in[20];
  float* out = (float*)d_out;

  // ---- workspace carve (~171 MB) ----
  char* w=(char*)d_ws;
  auto carve=[&](size_t n)->char*{ char* p=w; w += (n+255)&~(size_t)255; return p; };
  float* means=(float*)carve(65536);
  float* stdev=(float*)carve(65536);
  float* dec  =(float*)carve(256);
  unsigned short* zp=(unsigned short*)carve(512);              // zero page
  float* x    =(float*)carve((size_t)B_*NTOK*D_*4);            // 33.8 MB
  unsigned short* xhi=(unsigned short*)carve((size_t)B_*NTOK*D_*2); // 16.9
  unsigned short* xlo=(unsigned short*)carve((size_t)B_*NTOK*D_*2); // 16.9
  float* BIG  =(float*)carve((size_t)B_*TPAD*D_*4);            // 34.1 (qk/v/delta)
  constexpr size_t WTOT=6029312;
  unsigned short* whi=(unsigned short*)carve(WTOT*2);          // 12.1
  unsigned short* wlo=(unsigned short*)carve(WTOT*2);          // 12.1
  // Union arena: [PR|bkt|stk|ud|lse|lsetok] (attention) vs [hidHi|hidLo] (FFN)
  char* U = carve(45088768);
  float*          PR    =(float*)U;                                   // 17.04 MB
  unsigned char*  bkt   =(unsigned char*) (U+17039360);               // 0.53
  unsigned short* stk   =(unsigned short*)(U+17039360+532480);        // 1.06
  unsigned short* ud    =(unsigned short*)(U+17039360+532480+1064960);// 1.06
  float*          lseB  =(float*)(U+17039360+532480+2129920);         // 2.13
  float*          lsetok=(float*)(U+17039360+532480+2129920+2129920); // 0.53
  unsigned short* hidHi =(unsigned short*)U;                          // 22.54
  unsigned short* hidLo =(unsigned short*)(U+22544384);               // 22.54

  hipMemsetAsync(zp,0,512,stream);

  // weight arena offsets (elements); per-layer strides
  constexpr size_t oWemb=0, oWqk=262144, oWv=786432, oWo=1310720,
                   oWc1=1835008, oWc2=3932160;
  constexpr size_t Wsz=262144, C1sz=1048576, C2sz=1048576;

  // ---- split weights once (n = TOTAL elements) ----
  k_split<<<(262144+255)/256,256,0,stream>>>(Wemb,whi+oWemb,wlo+oWemb,262144);
  k_split<<<(524288+255)/256,256,0,stream>>>(Wqk, whi+oWqk, wlo+oWqk, 524288);
  k_split<<<(524288+255)/256,256,0,stream>>>(Wv,  whi+oWv,  wlo+oWv,  524288);
  k_split<<<(524288+255)/256,256,0,stream>>>(Wo,  whi+oWo,  wlo+oWo,  524288);
  k_split<<<(2097152+255)/256,256,0,stream>>>(Wc1, whi+oWc1, wlo+oWc1, 2097152);
  k_split<<<(2097152+255)/256,256,0,stream>>>(Wc2, whi+oWc2, wlo+oWc2, 2097152);

  // ---- embedding: GEMM writes x (no alias), then split x -> xhi/xlo ----
  k_revin<<<dim3(2,B_),256,0,stream>>>(xe,means,stdev);
  k_pack_tok<<<dim3(8,8,B_),256,0,stream>>>(xe,means,stdev,xhi,xlo);
  k_pack_marks<<<(B_*NMARK_*L_)/256,256,0,stream>>>(xm,xhi,xlo);
  k_gemm<0,false><<<dim3(4,129),256,0,stream>>>(xhi,xlo,whi+oWemb,wlo+oWemb,bemb,x,nullptr,nullptr,zp,16512,512,512);
  k_split<<<(B_*NTOK*D_+255)/256,256,0,stream>>>(x,xhi,xlo,B_*NTOK*D_);

  for(int l=0;l<NLAYERS_;l++){
    const unsigned short* Wqk_h=whi+oWqk+(size_t)l*Wsz, *Wqk_l2=wlo+oWqk+(size_t)l*Wsz;
    const unsigned short* Wv_h =whi+oWv +(size_t)l*Wsz, *Wv_l2 =wlo+oWv +(size_t)l*Wsz;
    const unsigned short* Wo_h =whi+oWo +(size_t)l*Wsz, *Wo_l2 =wlo+oWo +(size_t)l*Wsz;
    const unsigned short* Wc1_h=whi+oWc1+(size_t)l*C1sz,*Wc1_l2=wlo+oWc1+(size_t)l*C1sz;
    const unsigned short* Wc2_h=whi+oWc2+(size_t)l*C2sz,*Wc2_l2=wlo+oWc2+(size_t)l*C2sz;
    const float* bo_l =boP+(size_t)l*D_;
    const float* bc1_l=bc1+(size_t)l*DFF_;
    const float* bc2_l=bc2+(size_t)l*D_;
    const float* g1_l=g1+(size_t)l*D_;
    const float* b1_l=b1+(size_t)l*D_;
    const float* g2_l=g2+(size_t)l*D_;
    const float* b2_l=b2+(size_t)l*D_;
    const float* rot_l=rot+(size_t)l*DH_*NHASH_*(NB_/2);

    // qk projection
    k_gemm<0,true><<<dim3(4,130),256,0,stream>>>(xhi,xlo,Wqk_h,Wqk_l2,nullptr,BIG,nullptr,nullptr,zp,16640,512,512);
    // LSH routing + exact stable sort
    k_buckets<<<dim3(BH_,9),256,0,stream>>>(BIG,rot_l,bkt);
    k_sort<<<BH_,64,0,stream>>>(bkt,stk,ud);
    // LSE + dots (stored), then elementwise probs
    k_attn1<<<16640,256,0,stream>>>(BIG,stk,lseB,PR);
    k_wlse<<<(BH_*TPAD+255)/256,256,0,stream>>>(lseB,ud,lsetok);
    k_probs<<<(BH_*2080+255)/256,256,0,stream>>>(lseB,stk,lsetok,PR);
    // v projection overwrites qk; gather split-writes attn into xhi/xlo
    k_gemm<0,true><<<dim3(4,130),256,0,stream>>>(xhi,xlo,Wv_h,Wv_l2,nullptr,BIG,nullptr,nullptr,zp,16640,512,512);
    k_gather<<<dim3(B_,NTOK),256,0,stream>>>(BIG,stk,ud,PR,xhi,xlo);
    // output projection + residual LN (re-splits x)
    k_gemm<0,false><<<dim3(4,129),256,0,stream>>>(xhi,xlo,Wo_h,Wo_l2,bo_l,BIG,nullptr,nullptr,zp,16512,512,512);
    k_addln<<<16512,256,0,stream>>>(x,BIG,g1_l,b1_l,xhi,xlo);
    // FFN: 3 chunks of 5504 rows (hidden hi/lo lives in U; PR etc now dead)
    for(int ch=0; ch<3; ch++){
      size_t rs=(size_t)ch*5504;
      k_gemm<1,false><<<dim3(16,43),256,0,stream>>>(xhi+rs*D_,xlo+rs*D_,Wc1_h,Wc1_l2,bc1_l,nullptr,hidHi,hidLo,zp,5504,2048,512);
      k_gemm<0,false><<<dim3(4,43),256,0,stream>>>(hidHi,hidLo,Wc2_h,Wc2_l2,bc2_l,BIG+rs*D_,nullptr,nullptr,zp,5504,512,2048);
    }
    k_addln<<<16512,256,0,stream>>>(x,BIG,g2_l,b2_l,xhi,xlo);
  }

  k_dec<<<B_,256,0,stream>>>(x,gF,bF,Wp,bp,dec);
  k_out<<<2048,256,0,stream>>>(dec,means,stdev,out);
}

// Round 8
// 1735.756 us; speedup vs baseline: 2.4189x; 1.1109x over previous
//
#include <hip/hip_runtime.h>
#include <stdint.h>

// ============================================================================
// Reformer/LSH iTransformer forward on MI355X (gfx950). ALL I/O FP32.
// R8 = R7 with k_gemm's K-loop double-buffered: global_load_lds prefetch of
// tile k+1 overlaps MFMA on tile k; one barrier per K-step. MFMA order
// unchanged -> bit-identical to R7 (absmax 0.005859375).
// ============================================================================

constexpr int B_=32, L_=512, E_=512, NMARK_=4, D_=512, DFF_=2048, NLAYERS_=2;
constexpr int NTOK=516, TPAD=520, DH_=64, NB_=130, NHASH_=4;
constexpr int BH_=256, NCH_=520;

typedef __attribute__((ext_vector_type(8))) short v8s;
typedef __attribute__((ext_vector_type(4))) float v4f;

typedef __attribute__((address_space(1))) const unsigned int gu32;
typedef __attribute__((address_space(3))) unsigned int lu32;
static __device__ __forceinline__ void gload_lds16(const void* g, void* l){
  __builtin_amdgcn_global_load_lds((gu32*)g, (lu32*)l, 16, 0, 0);
}

static __device__ __forceinline__ unsigned short f2bf(float f){
  union{float f; unsigned int u;} c; c.f=f;
  unsigned int u=c.u;
  return (unsigned short)((u + 0x7fffu + ((u>>16)&1u))>>16);  // RNE
}
static __device__ __forceinline__ float bf2f(unsigned short h){
  union{unsigned int u; float f;} c; c.u=((unsigned int)h)<<16; return c.f;
}
static __device__ __forceinline__ float blockReduce256(float v, float* red, int tid){
  for(int o=32;o;o>>=1) v += __shfl_down(v,o,64);
  __syncthreads();
  if((tid&63)==0) red[tid>>6]=v;
  __syncthreads();
  return red[0]+red[1]+red[2]+red[3];
}

// ---------------- generic fp32 -> (hi,lo) bf16 split ------------------------
__global__ void k_split(const float* __restrict__ src, unsigned short* __restrict__ hi,
    unsigned short* __restrict__ lo, int n){
  int idx=blockIdx.x*256+threadIdx.x;
  if(idx>=n) return;
  float v=src[idx];
  unsigned short h=f2bf(v);
  hi[idx]=h; lo[idx]=f2bf(v-bf2f(h));
}

// ---------------- RevIN stats over L per (b,e) ------------------------------
__global__ __launch_bounds__(256) void k_revin(const float* __restrict__ xe,
    float* __restrict__ means, float* __restrict__ stdev){
  int b=blockIdx.y;
  int e=blockIdx.x*256+threadIdx.x;
  const float* p = xe + (size_t)b*L_*E_ + e;
  float s=0.f,s2=0.f;
  for(int l=0;l<L_;l++){ float v=p[(size_t)l*E_]; s+=v; s2+=v*v; }
  float m=s*(1.f/512.f);
  float var=s2*(1.f/512.f)-m*m;
  var = var>0.f? var:0.f;
  means[b*E_+e]=m;
  stdev[b*E_+e]=sqrtf(var+1e-5f);
}

// ------- transpose x_enc -> token rows with RevIN, split-write hi/lo --------
__global__ __launch_bounds__(256) void k_pack_tok(const float* __restrict__ xe,
     const float* __restrict__ means, const float* __restrict__ stdev,
     unsigned short* __restrict__ hi, unsigned short* __restrict__ lo){
  __shared__ float tile[64][65];
  int b=blockIdx.z;
  int ct=blockIdx.x*64, lt=blockIdx.y*64;
  int tid=threadIdx.x;
  int i=tid>>2, j0=(tid&3)*16;
  {
    const float* src = xe + ((size_t)b*L_ + lt + i)*E_ + ct + j0;
    float tmp[16];
    *(float4*)&tmp[0]  = *(const float4*)(src);
    *(float4*)&tmp[4]  = *(const float4*)(src+4);
    *(float4*)&tmp[8]  = *(const float4*)(src+8);
    *(float4*)&tmp[12] = *(const float4*)(src+12);
    for(int j=0;j<16;j++) tile[i][j0+j]=tmp[j];
  }
  __syncthreads();
  {
    float ms=means[b*E_+ct+i];
    float sd=stdev[b*E_+ct+i];
    unsigned short hs[16], ls[16];
    for(int j=0;j<16;j++){
      float v=(tile[j0+j][i]-ms)/sd;
      unsigned short hh=f2bf(v);
      hs[j]=hh; ls[j]=f2bf(v-bf2f(hh));
    }
    size_t off = ((size_t)b*NTOK + ct + i)*(size_t)L_ + lt + j0;
    *(uint4*)&hi[off]   = *(uint4*)&hs[0];
    *(uint4*)&hi[off+8] = *(uint4*)&hs[8];
    *(uint4*)&lo[off]   = *(uint4*)&ls[0];
    *(uint4*)&lo[off+8] = *(uint4*)&ls[8];
  }
}

__global__ void k_pack_marks(const float* __restrict__ xm,
    unsigned short* __restrict__ hi, unsigned short* __restrict__ lo){
  int idx=blockIdx.x*256+threadIdx.x; // 32*4*512
  int l=idx&511, j=(idx>>9)&3, b=idx>>11;
  float v = xm[((size_t)b*L_ + l)*NMARK_ + j];
  unsigned short hh=f2bf(v);
  size_t off=((size_t)b*NTOK + E_ + j)*(size_t)L_ + l;
  hi[off]=hh; lo[off]=f2bf(v-bf2f(hh));
}

// ------ 128x128 bf16 MFMA GEMM, double-buffered global_load_lds pipeline ----
// C = (Ahi+Alo)@(Bhi+Blo)^T + bias, 3 MFMAs (AloBhi + AhiBlo + AhiBhi).
// OUTMODE 0: fp32 C. 1: relu + split hi/lo.  (no in-place alias modes!)
// TPADDED: M rows indexed b*520+t, A from compact [b*516+t], t>=516 -> zeropad.
template<int OUTMODE, bool TPADDED>
__global__ __launch_bounds__(256) void k_gemm(
    const unsigned short* __restrict__ Ahi, const unsigned short* __restrict__ Alo,
    const unsigned short* __restrict__ Bhi, const unsigned short* __restrict__ Blo,
    const float* __restrict__ bias, float* __restrict__ Cf,
    unsigned short* __restrict__ Chi, unsigned short* __restrict__ Clo,
    const unsigned short* __restrict__ zeropad,
    int M, int N, int K)
{
  // [buf][tile][128 rows x 32 k] ; tiles: 0=Ahi 1=Alo 2=Bhi 3=Blo ; 64 KB
  __shared__ __align__(16) unsigned short LDS[2][4][128*32];
  const int m0=blockIdx.y*128, n0=blockIdx.x*128;
  const int tid=threadIdx.x, lane=tid&63, wave=tid>>6;
  const int wm=(wave>>1)*64, wn=(wave&1)*64;

  // wave w DMAs tile w; call j covers rows j*16..j*16+15;
  // lane i -> row j*16 + (i>>2), 16B seg (i&3). HW: lds base + lane*16B.
  const unsigned short* srcp = (wave==0)?Ahi:(wave==1)?Alo:(wave==2)?Bhi:Blo;
  const int rsub=lane>>2, seg=(lane&3)*8;
  const unsigned short* gp[8]; int stp[8];
  #pragma unroll
  for(int j=0;j<8;j++){
    int row=j*16+rsub;
    if(wave<2){
      size_t ao; bool valid=true;
      int g=m0+row;
      if constexpr (TPADDED){
        int b=g/TPAD; int t=g-b*TPAD; valid=(t<NTOK);
        ao=((size_t)b*NTOK + (valid?t:0))*(size_t)K;
      } else ao=(size_t)g*(size_t)K;
      gp[j]= valid ? (srcp+ao+seg) : (zeropad+seg);
      stp[j]= valid ? 32 : 0;
    } else {
      gp[j]= srcp + (size_t)(n0+row)*(size_t)K + seg;
      stp[j]=32;
    }
  }

  v4f acc[4][4];
  for(int i=0;i<4;i++)for(int j=0;j<4;j++) acc[i][j]=(v4f){0.f,0.f,0.f,0.f};
  const int am = wm + (lane&15);
  const int bn = wn + (lane&15);
  const int kk = (lane>>4)*8;
  const int nIter=K/32;

  // prologue: DMA tile 0 into buf 0
  #pragma unroll
  for(int j=0;j<8;j++){ gload_lds16(gp[j], &LDS[0][wave][j*512]); gp[j]+=stp[j]; }

  for(int k=0;k<nIter;k++){
    __syncthreads();   // drains vmcnt(0): buf[k&1] DMA complete, all waves
    if(k+1<nIter){     // prefetch next tile into the other buffer
      unsigned short* nxt=&LDS[(k+1)&1][wave][0];
      #pragma unroll
      for(int j=0;j<8;j++){ gload_lds16(gp[j], nxt+j*512); gp[j]+=stp[j]; }
    }
    const unsigned short* cur=&LDS[k&1][0][0];
    v8s a[4], al[4], b[4], bl[4];
    for(int t=0;t<4;t++){
      a[t] =*(const v8s*)&cur[        (am+t*16)*32+kk];
      al[t]=*(const v8s*)&cur[ 4096 + (am+t*16)*32+kk];
      b[t] =*(const v8s*)&cur[ 8192 + (bn+t*16)*32+kk];
      bl[t]=*(const v8s*)&cur[12288 + (bn+t*16)*32+kk];
    }
    for(int mt=0;mt<4;mt++)for(int nt=0;nt<4;nt++){
      acc[mt][nt]=__builtin_amdgcn_mfma_f32_16x16x32_bf16(al[mt],b[nt], acc[mt][nt],0,0,0);
      acc[mt][nt]=__builtin_amdgcn_mfma_f32_16x16x32_bf16(a[mt], bl[nt],acc[mt][nt],0,0,0);
      acc[mt][nt]=__builtin_amdgcn_mfma_f32_16x16x32_bf16(a[mt], b[nt], acc[mt][nt],0,0,0);
    }
  }
  // C/D mapping: col=lane&15, row=(lane>>4)*4+r
  for(int mt=0;mt<4;mt++)for(int nt=0;nt<4;nt++){
    int col = n0 + wn + nt*16 + (lane&15);
    int rb  = m0 + wm + mt*16 + (lane>>4)*4;
    float bv = bias ? bias[col] : 0.f;
    for(int r=0;r<4;r++){
      float v = acc[mt][nt][r] + bv;
      size_t off=(size_t)(rb+r)*N + col;
      if constexpr (OUTMODE==0){
        Cf[off]=v;
      } else {
        v = v>0.f ? v : 0.f;
        unsigned short hh=f2bf(v);
        Chi[off]=hh; Clo[off]=f2bf(v-bf2f(hh));
      }
    }
  }
}

// ---------------- LSH buckets: wave=hash, thread=token, rot via s_load ------
__global__ __launch_bounds__(256) void k_buckets(const float* __restrict__ qk,
    const float* __restrict__ rot, unsigned char* __restrict__ buckets){
  __shared__ float qkT[64*69];   // [f][t], stride 69 -> conflict-free reads
  int bh=blockIdx.x, tc=blockIdx.y;
  int b=bh>>3, hd=bh&7;
  int t0=tc*64;
  int tid=threadIdx.x;
  for(int j=tid;j<4096;j+=256){
    int t=j>>6, f=j&63;
    int tg=t0+t;
    qkT[f*69+t] = (tg<TPAD)? qk[((size_t)b*TPAD+tg)*(size_t)D_ + hd*64 + f] : 0.f;
  }
  __syncthreads();
  int h = __builtin_amdgcn_readfirstlane(tid>>6);   // wave-uniform hash
  int t = tid&63;
  const float* rh = rot + h*65;                     // rot[f][4][65]
  float acc[65];
  #pragma unroll
  for(int i=0;i<65;i++) acc[i]=0.f;
  for(int f=0;f<64;f++){
    float q = qkT[f*69+t];
    #pragma unroll
    for(int i=0;i<65;i++) acc[i] += q * rh[f*260+i];  // rh uniform -> s_load
  }
  float bv=-3.4e38f; int bi=0x7fffffff;
  #pragma unroll
  for(int i=0;i<65;i++){
    float r=acc[i]; float cv; int ci;
    if(r>=-r){cv=r;ci=i;}else{cv=-r;ci=i+65;}
    if(cv>bv||(cv==bv&&ci<bi)){bv=cv;bi=ci;}
  }
  int tg=t0+t;
  if(tg<TPAD) buckets[((size_t)bh*4+h)*TPAD+tg]=(unsigned char)bi;
}

// ---------------- stable counting sort == jnp.argsort(bucket*t+pos) ---------
__global__ __launch_bounds__(64) void k_sort(const unsigned char* __restrict__ buckets,
    unsigned short* __restrict__ sticker, unsigned short* __restrict__ undo){
  __shared__ int cnt[520];
  __shared__ int offs[520];
  int bh=blockIdx.x, tid=threadIdx.x;
  const unsigned char* bb = buckets + (size_t)bh*4*TPAD;
  for(int i=tid;i<520;i+=64) cnt[i]=0;
  __syncthreads();
  for(int i=tid;i<2080;i+=64){
    int h=i/TPAD;
    atomicAdd(&cnt[(int)bb[i]+h*NB_],1);
  }
  __syncthreads();
  if(tid==0){ int s=0; for(int k2=0;k2<520;k2++){ offs[k2]=s; s+=cnt[k2]; } }
  __syncthreads();
  if(tid<4){
    int h=tid;
    unsigned short* stk = sticker + (size_t)bh*2080;
    unsigned short* ud  = undo    + (size_t)bh*2080;
    for(int p=0;p<TPAD;p++){
      int key = (int)bb[h*TPAD+p] + h*NB_;
      int j = offs[key]++;
      stk[j] = (unsigned short)(h*TPAD+p);
      ud[h*TPAD+p] = (unsigned short)j;
    }
  }
}

// -------- attention pass 1: per-chunk LSE + store masked dots into PR -------
__global__ __launch_bounds__(256) void k_attn1(const float* __restrict__ qk,
    const unsigned short* __restrict__ sticker, float* __restrict__ lse,
    float* __restrict__ PR){
  __shared__ float rows[8][8][68];
  __shared__ int   sts[8][8];
  __shared__ float n2s[8][8];
  int tid=threadIdx.x, grp=tid>>5, lane=tid&31;
  int gid=blockIdx.x*8+grp;
  int bh=gid/NCH_, c=gid-bh*NCH_;
  int b=bh>>3, hd=bh&7;
  const unsigned short* stk = sticker + (size_t)bh*2080;
  if(lane<8){
    int r=lane;
    int cprev=(c+NCH_-1)%NCH_;
    int j=(r<4)? c*4+r : cprev*4+(r-4);
    sts[grp][r]=(int)stk[j]%TPAD;
  }
  __syncthreads();
  #pragma unroll
  for(int it=0; it<2; it++){
    int j=lane+32*it;
    int r=j>>3, f0=(j&7)*8;
    const float* src=qk+((size_t)b*TPAD+sts[grp][r])*(size_t)D_+hd*64+f0;
    *(float4*)&rows[grp][r][f0]   = *(const float4*)src;
    *(float4*)&rows[grp][r][f0+4] = *(const float4*)(src+4);
  }
  __syncthreads();
  {
    int r=lane>>2, part=lane&3;
    float s=0.f;
    #pragma unroll
    for(int f=part*16; f<part*16+16; f++){ float v=rows[grp][r][f]; s+=v*v; }
    s+=__shfl_xor(s,1,64); s+=__shfl_xor(s,2,64);
    if(part==0) n2s[grp][r]=s;
  }
  __syncthreads();
  int qi=lane>>3, kj=lane&7;
  float dt=0.f;
  #pragma unroll
  for(int f=0;f<64;f++) dt += rows[grp][qi][f]*rows[grp][kj][f];
  float kn=n2s[grp][kj]; kn = kn>1e-24f? kn:1e-24f;
  dt = dt/sqrtf(kn)*0.125f;
  if(sts[grp][qi]==sts[grp][kj]) dt=-5e4f;
  PR[((size_t)bh*2080 + c*4 + qi)*8 + kj] = dt;
  float mx=dt;
  for(int o=1;o<8;o<<=1){ float om=__shfl_xor(mx,o,64); mx=om>mx?om:mx; }
  float sm=expf(dt-mx);
  for(int o=1;o<8;o<<=1) sm+=__shfl_xor(sm,o,64);
  if(kj==0) lse[(size_t)bh*2080 + c*4 + qi] = mx + logf(sm);
}

// ---------------- per-token LSE over the 4 hash rounds ----------------------
__global__ void k_wlse(const float* __restrict__ lse, const unsigned short* __restrict__ undo,
    float* __restrict__ lsetok){
  int idx=blockIdx.x*256+threadIdx.x;   // BH*520
  if(idx>=BH_*TPAD) return;
  int bh=idx/TPAD, p=idx-bh*TPAD;
  const unsigned short* u=undo+(size_t)bh*2080;
  const float* ls=lse+(size_t)bh*2080;
  float l0=ls[u[p]], l1=ls[u[TPAD+p]], l2=ls[u[2*TPAD+p]], l3=ls[u[3*TPAD+p]];
  float mx=fmaxf(fmaxf(l0,l1),fmaxf(l2,l3));
  lsetok[idx]=mx+logf(expf(l0-mx)+expf(l1-mx)+expf(l2-mx)+expf(l3-mx));
}

// ---------------- dots -> probs (elementwise, in-place in PR) ---------------
__global__ void k_probs(const float* __restrict__ lse, const unsigned short* __restrict__ sticker,
    const float* __restrict__ lsetok, float* __restrict__ PR){
  int j=blockIdx.x*256+threadIdx.x;     // BH*2080 slots
  if(j>=BH_*2080) return;
  int bh=j/2080;
  float L=lse[j];
  int p=(int)sticker[j]%TPAD;
  float w=expf(L-lsetok[bh*TPAD+p]);
  float* pr=PR+(size_t)j*8;
  float4 d0=*(float4*)pr, d1=*(float4*)(pr+4);
  d0.x=expf(d0.x-L)*w; d0.y=expf(d0.y-L)*w; d0.z=expf(d0.z-L)*w; d0.w=expf(d0.w-L)*w;
  d1.x=expf(d1.x-L)*w; d1.y=expf(d1.y-L)*w; d1.z=expf(d1.z-L)*w; d1.w=expf(d1.w-L)*w;
  *(float4*)pr=d0; *(float4*)(pr+4)=d1;
}

// ------- attention gather: out[b,t,:] = sum P*v, split-write hi/lo ----------
__global__ __launch_bounds__(256) void k_gather(const float* __restrict__ v,
    const unsigned short* __restrict__ sticker, const unsigned short* __restrict__ undo,
    const float* __restrict__ PR, unsigned short* __restrict__ ahi,
    unsigned short* __restrict__ alo){
  __shared__ int   ridx[8][32];
  __shared__ float pval[8][32];
  int b=blockIdx.x, t=blockIdx.y;
  int tid=threadIdx.x, hd=tid>>5, l=tid&31;
  int bh=b*8+hd;
  const unsigned short* stk = sticker + (size_t)bh*2080;
  const unsigned short* ud  = undo    + (size_t)bh*2080;
  {
    int h=l>>3, kj=l&7;
    int j = (int)ud[h*TPAD+t];
    int c = j>>2;
    int slot = (kj<4)? (c*4+kj) : (((c+NCH_-1)%NCH_)*4 + (kj-4));
    ridx[hd][l] = (int)stk[slot]%TPAD;
    pval[hd][l] = PR[((size_t)bh*2080 + j)*8 + kj];
  }
  __syncthreads();
  int f0=l*2;
  float a0=0.f, a1=0.f;
  const float* vb = v + (size_t)b*TPAD*D_ + hd*64 + f0;
  for(int i=0;i<32;i++){
    const float* vr = vb + (size_t)ridx[hd][i]*D_;
    float p=pval[hd][i];
    a0 += p*vr[0];
    a1 += p*vr[1];
  }
  size_t off = ((size_t)b*NTOK + t)*(size_t)D_ + hd*64 + f0;
  unsigned short h0=f2bf(a0), h1=f2bf(a1);
  ahi[off]=h0; ahi[off+1]=h1;
  alo[off]=f2bf(a0-bf2f(h0)); alo[off+1]=f2bf(a1-bf2f(h1));
}

// -------- x = LN(x + delta)*g + b ; also split-write hi/lo ------------------
__global__ __launch_bounds__(256) void k_addln(float* __restrict__ x,
    const float* __restrict__ delta, const float* __restrict__ g,
    const float* __restrict__ bb, unsigned short* __restrict__ xhi,
    unsigned short* __restrict__ xlo){
  __shared__ float red[4];
  int row=blockIdx.x, tid=threadIdx.x;
  size_t base=(size_t)row*D_;
  float v0=x[base+tid]+delta[base+tid];
  float v1=x[base+tid+256]+delta[base+tid+256];
  float m=blockReduce256(v0+v1,red,tid)*(1.f/512.f);
  float d0=v0-m, d1=v1-m;
  float var=blockReduce256(d0*d0+d1*d1,red,tid)*(1.f/512.f);
  float inv=1.f/sqrtf(var+1e-5f);
  float y0=d0*inv*g[tid]    +bb[tid];
  float y1=d1*inv*g[tid+256]+bb[tid+256];
  x[base+tid]=y0; x[base+tid+256]=y1;
  unsigned short h0=f2bf(y0), h1=f2bf(y1);
  xhi[base+tid]=h0; xhi[base+tid+256]=h1;
  xlo[base+tid]=f2bf(y0-bf2f(h0)); xlo[base+tid+256]=f2bf(y1-bf2f(h1));
}

// ---------------- final LN on last token + projection -----------------------
__global__ __launch_bounds__(256) void k_dec(const float* __restrict__ x,
    const float* __restrict__ gF, const float* __restrict__ bF,
    const float* __restrict__ Wp, const float* __restrict__ bp,
    float* __restrict__ dec){
  __shared__ float red[4];
  int b=blockIdx.x, tid=threadIdx.x;
  const float* row = x + ((size_t)b*NTOK + (NTOK-1))*(size_t)D_;
  float v0=row[tid], v1=row[tid+256];
  float m=blockReduce256(v0+v1,red,tid)*(1.f/512.f);
  float d0=v0-m, d1=v1-m;
  float var=blockReduce256(d0*d0+d1*d1,red,tid)*(1.f/512.f);
  float inv=1.f/sqrtf(var+1e-5f);
  float y0=d0*inv*gF[tid]    +bF[tid];
  float y1=d1*inv*gF[tid+256]+bF[tid+256];
  float dd=blockReduce256(y0*Wp[tid]+y1*Wp[tid+256],red,tid);
  if(tid==0) dec[b]=dd+bp[0];
}

__global__ void k_out(const float* __restrict__ dec, const float* __restrict__ means,
    const float* __restrict__ stdev, float* __restrict__ out){
  int idx=blockIdx.x*256+threadIdx.x;
  int e=idx&511, j=(idx>>9)&31, i=idx>>14;
  out[idx]=dec[j]*stdev[i*E_+e]+means[i*E_+e];
}

// ============================================================================
extern "C" void kernel_launch(void* const* d_in, const int* in_sizes, int n_in,
                              void* d_out, int out_size, void* d_ws, size_t ws_size,
                              hipStream_t stream){
  (void)in_sizes; (void)n_in; (void)out_size; (void)ws_size;
  const float* xe   = (const float*)d_in[0];
  const float* xm   = (const float*)d_in[1];
  const float* Wemb = (const float*)d_in[2];
  const float* bemb = (const float*)d_in[3];
  const float* Wqk  = (const float*)d_in[4];
  const float* Wv   = (const float*)d_in[5];
  const float* Wo   = (const float*)d_in[6];
  const float* boP  = (const float*)d_in[7];
  const float* Wc1  = (const float*)d_in[8];
  const float* bc1  = (const float*)d_in[9];
  const float* Wc2  = (const float*)d_in[10];
  const float* bc2  = (const float*)d_in[11];
  const float* g1   = (const float*)d_in[12];
  const float* b1   = (const float*)d_in[13];
  const float* g2   = (const float*)d_in[14];
  const float* b2   = (const float*)d_in[15];
  const float* gF   = (const float*)d_in[16];
  const float* bF   = (const float*)d_in[17];
  const float* Wp   = (const float*)d_in[18];
  const float* bp   = (const float*)d_in[19];
  const float* rot  = (const float*)d_in[20];
  float* out = (float*)d_out;

  // ---- workspace carve (~171 MB) ----
  char* w=(char*)d_ws;
  auto carve=[&](size_t n)->char*{ char* p=w; w += (n+255)&~(size_t)255; return p; };
  float* means=(float*)carve(65536);
  float* stdev=(float*)carve(65536);
  float* dec  =(float*)carve(256);
  unsigned short* zp=(unsigned short*)carve(512);              // zero page
  float* x    =(float*)carve((size_t)B_*NTOK*D_*4);            // 33.8 MB
  unsigned short* xhi=(unsigned short*)carve((size_t)B_*NTOK*D_*2); // 16.9
  unsigned short* xlo=(unsigned short*)carve((size_t)B_*NTOK*D_*2); // 16.9
  float* BIG  =(float*)carve((size_t)B_*TPAD*D_*4);            // 34.1 (qk/v/delta)
  constexpr size_t WTOT=6029312;
  unsigned short* whi=(unsigned short*)carve(WTOT*2);          // 12.1
  unsigned short* wlo=(unsigned short*)carve(WTOT*2);          // 12.1
  // Union arena: [PR|bkt|stk|ud|lse|lsetok] (attention) vs [hidHi|hidLo] (FFN)
  char* U = carve(45088768);
  float*          PR    =(float*)U;                                   // 17.04 MB
  unsigned char*  bkt   =(unsigned char*) (U+17039360);               // 0.53
  unsigned short* stk   =(unsigned short*)(U+17039360+532480);        // 1.06
  unsigned short* ud    =(unsigned short*)(U+17039360+532480+1064960);// 1.06
  float*          lseB  =(float*)(U+17039360+532480+2129920);         // 2.13
  float*          lsetok=(float*)(U+17039360+532480+2129920+2129920); // 0.53
  unsigned short* hidHi =(unsigned short*)U;                          // 22.54
  unsigned short* hidLo =(unsigned short*)(U+22544384);               // 22.54

  hipMemsetAsync(zp,0,512,stream);

  // weight arena offsets (elements); per-layer strides
  constexpr size_t oWemb=0, oWqk=262144, oWv=786432, oWo=1310720,
                   oWc1=1835008, oWc2=3932160;
  constexpr size_t Wsz=262144, C1sz=1048576, C2sz=1048576;

  // ---- split weights once (n = TOTAL elements) ----
  k_split<<<(262144+255)/256,256,0,stream>>>(Wemb,whi+oWemb,wlo+oWemb,262144);
  k_split<<<(524288+255)/256,256,0,stream>>>(Wqk, whi+oWqk, wlo+oWqk, 524288);
  k_split<<<(524288+255)/256,256,0,stream>>>(Wv,  whi+oWv,  wlo+oWv,  524288);
  k_split<<<(524288+255)/256,256,0,stream>>>(Wo,  whi+oWo,  wlo+oWo,  524288);
  k_split<<<(2097152+255)/256,256,0,stream>>>(Wc1, whi+oWc1, wlo+oWc1, 2097152);
  k_split<<<(2097152+255)/256,256,0,stream>>>(Wc2, whi+oWc2, wlo+oWc2, 2097152);

  // ---- embedding: GEMM writes x (no alias), then split x -> xhi/xlo ----
  k_revin<<<dim3(2,B_),256,0,stream>>>(xe,means,stdev);
  k_pack_tok<<<dim3(8,8,B_),256,0,stream>>>(xe,means,stdev,xhi,xlo);
  k_pack_marks<<<(B_*NMARK_*L_)/256,256,0,stream>>>(xm,xhi,xlo);
  k_gemm<0,false><<<dim3(4,129),256,0,stream>>>(xhi,xlo,whi+oWemb,wlo+oWemb,bemb,x,nullptr,nullptr,zp,16512,512,512);
  k_split<<<(B_*NTOK*D_+255)/256,256,0,stream>>>(x,xhi,xlo,B_*NTOK*D_);

  for(int l=0;l<NLAYERS_;l++){
    const unsigned short* Wqk_h=whi+oWqk+(size_t)l*Wsz, *Wqk_l2=wlo+oWqk+(size_t)l*Wsz;
    const unsigned short* Wv_h =whi+oWv +(size_t)l*Wsz, *Wv_l2 =wlo+oWv +(size_t)l*Wsz;
    const unsigned short* Wo_h =whi+oWo +(size_t)l*Wsz, *Wo_l2 =wlo+oWo +(size_t)l*Wsz;
    const unsigned short* Wc1_h=whi+oWc1+(size_t)l*C1sz,*Wc1_l2=wlo+oWc1+(size_t)l*C1sz;
    const unsigned short* Wc2_h=whi+oWc2+(size_t)l*C2sz,*Wc2_l2=wlo+oWc2+(size_t)l*C2sz;
    const float* bo_l =boP+(size_t)l*D_;
    const float* bc1_l=bc1+(size_t)l*DFF_;
    const float* bc2_l=bc2+(size_t)l*D_;
    const float* g1_l=g1+(size_t)l*D_;
    const float* b1_l=b1+(size_t)l*D_;
    const float* g2_l=g2+(size_t)l*D_;
    const float* b2_l=b2+(size_t)l*D_;
    const float* rot_l=rot+(size_t)l*DH_*NHASH_*(NB_/2);

    // qk projection
    k_gemm<0,true><<<dim3(4,130),256,0,stream>>>(xhi,xlo,Wqk_h,Wqk_l2,nullptr,BIG,nullptr,nullptr,zp,16640,512,512);
    // LSH routing + exact stable sort
    k_buckets<<<dim3(BH_,9),256,0,stream>>>(BIG,rot_l,bkt);
    k_sort<<<BH_,64,0,stream>>>(bkt,stk,ud);
    // LSE + dots (stored), then elementwise probs
    k_attn1<<<16640,256,0,stream>>>(BIG,stk,lseB,PR);
    k_wlse<<<(BH_*TPAD+255)/256,256,0,stream>>>(lseB,ud,lsetok);
    k_probs<<<(BH_*2080+255)/256,256,0,stream>>>(lseB,stk,lsetok,PR);
    // v projection overwrites qk; gather split-writes attn into xhi/xlo
    k_gemm<0,true><<<dim3(4,130),256,0,stream>>>(xhi,xlo,Wv_h,Wv_l2,nullptr,BIG,nullptr,nullptr,zp,16640,512,512);
    k_gather<<<dim3(B_,NTOK),256,0,stream>>>(BIG,stk,ud,PR,xhi,xlo);
    // output projection + residual LN (re-splits x)
    k_gemm<0,false><<<dim3(4,129),256,0,stream>>>(xhi,xlo,Wo_h,Wo_l2,bo_l,BIG,nullptr,nullptr,zp,16512,512,512);
    k_addln<<<16512,256,0,stream>>>(x,BIG,g1_l,b1_l,xhi,xlo);
    // FFN: 3 chunks of 5504 rows (hidden hi/lo lives in U; PR etc now dead)
    for(int ch=0; ch<3; ch++){
      size_t rs=(size_t)ch*5504;
      k_gemm<1,false><<<dim3(16,43),256,0,stream>>>(xhi+rs*D_,xlo+rs*D_,Wc1_h,Wc1_l2,bc1_l,nullptr,hidHi,hidLo,zp,5504,2048,512);
      k_gemm<0,false><<<dim3(4,43),256,0,stream>>>(hidHi,hidLo,Wc2_h,Wc2_l2,bc2_l,BIG+rs*D_,nullptr,nullptr,zp,5504,512,2048);
    }
    k_addln<<<16512,256,0,stream>>>(x,BIG,g2_l,b2_l,xhi,xlo);
  }

  k_dec<<<B_,256,0,stream>>>(x,gF,bF,Wp,bp,dec);
  k_out<<<2048,256,0,stream>>>(dec,means,stdev,out);
}